// Round 1
// baseline (3996.836 us; speedup 1.0000x reference)
//
#include <hip/hip_runtime.h>
#include <math.h>

// Problem constants
#define NN 100000   // nodes
#define INF 128     // input features
#define DD  512     // hidden dim
#define GG  64      // graphs
#define CC  10      // classes

// ---------------------------------------------------------------------------
// small utility kernels
// ---------------------------------------------------------------------------

__global__ void zero_k(float* __restrict__ p, int n) {
    int i = blockIdx.x * blockDim.x + threadIdx.x;
    if (i < n) p[i] = 0.0f;
}

// batch is sorted; starts[g] = lower_bound(batch, g), starts[GG] = NN
__global__ void bounds_k(const int* __restrict__ batch, int* __restrict__ starts) {
    int g = threadIdx.x;
    if (g <= GG) {
        int lo = 0, hi = NN;
        while (lo < hi) {
            int mid = (lo + hi) >> 1;
            if (batch[mid] < g) lo = mid + 1; else hi = mid;
        }
        starts[g] = lo;
    }
}

// column sums / sum-of-squares of x (NN x INF) -> stats[0..127]=sum, [128..255]=sumsq
__global__ void colstats_x(const float* __restrict__ x, float* __restrict__ stats) {
    int col = threadIdx.x; // blockDim.x == 128
    float s = 0.f, q = 0.f;
    for (int row = blockIdx.x; row < NN; row += gridDim.x) {
        float v = x[(size_t)row * INF + col];
        s += v; q += v * v;
    }
    atomicAdd(&stats[col], s);
    atomicAdd(&stats[INF + col], q);
}

// s = gamma * rsqrt(var+eps); t = beta - mean*s   (biased var, matches jnp.var)
__global__ void prep_st(const float* __restrict__ stats, int K,
                        const float* __restrict__ gamma, const float* __restrict__ beta,
                        float* __restrict__ s, float* __restrict__ t) {
    int j = blockIdx.x * blockDim.x + threadIdx.x;
    if (j < K) {
        const float invN = 1.0f / (float)NN;
        float mean = stats[j] * invN;
        float var  = stats[K + j] * invN - mean * mean;
        float sv   = gamma[j] * rsqrtf(var + 1e-5f);
        s[j] = sv;
        t[j] = beta[j] - mean * sv;
    }
}

// Wp[k][j] = s[k] * W[k][j]   (W is K x 512)
__global__ void fold_w(const float* __restrict__ s, const float* __restrict__ W,
                       float* __restrict__ Wp, int K) {
    int i = blockIdx.x * blockDim.x + threadIdx.x;
    if (i < K * DD) Wp[i] = s[i >> 9] * W[i];   // i>>9 == row since DD==512
}

// bp[j] = b[j] + sum_k t[k]*W[k][j]
__global__ void fold_b(const float* __restrict__ t, const float* __restrict__ W,
                       const float* __restrict__ b, float* __restrict__ bp, int K) {
    int j = blockIdx.x * blockDim.x + threadIdx.x;
    if (j < DD) {
        float acc = b[j];
        for (int k = 0; k < K; k++) acc += t[k] * W[(size_t)k * DD + j];
        bp[j] = acc;
    }
}

// ---------------------------------------------------------------------------
// main GEMM: Hout[n,:] = relu(A[n,:] @ W + bias),  A is NN x K, W is K x 512.
// Row-block-local (32 rows/block, staged to LDS first) => in-place safe
// (A may alias Hout). Optional epilogue accumulates per-column sum/sumsq of
// the relu'd output into stats[0..511]/stats[512..1023] (must be pre-zeroed).
// block = 256 threads = 4 waves; wave r owns rows r*8..r*8+7, lane c owns
// cols c*8..c*8+7. LDS broadcast reads (all lanes of a wave read same addr).
// ---------------------------------------------------------------------------
template <int K, bool STATS>
__global__ __launch_bounds__(256, 2)
void gemm_rb(const float* __restrict__ A, const float* __restrict__ W,
             const float* __restrict__ bias, float* __restrict__ Hout,
             float* __restrict__ stats) {
    __shared__ float lds[32 * K];
    const int t = threadIdx.x;
    const int row0 = blockIdx.x * 32;

    // stage the block's 32 input rows (32*K floats), float4-coalesced
    {
        const float* Ablk = A + (size_t)row0 * K;
        for (int i = t * 4; i < 32 * K; i += 256 * 4)
            *(float4*)&lds[i] = *(const float4*)&Ablk[i];
    }
    __syncthreads();

    const int r = t >> 6;   // wave id 0..3
    const int c = t & 63;   // col-group 0..63

    float acc[8][8];
#pragma unroll
    for (int i = 0; i < 8; i++)
#pragma unroll
        for (int j = 0; j < 8; j++) acc[i][j] = 0.0f;

    const float* Wc = W + c * 8;

    for (int k0 = 0; k0 < K; k0 += 4) {
        float4 a[8];
#pragma unroll
        for (int i = 0; i < 8; i++)
            a[i] = *(const float4*)&lds[(r * 8 + i) * K + k0];   // broadcast
#pragma unroll
        for (int kk = 0; kk < 4; kk++) {
            float4 wA = *(const float4*)(Wc + (size_t)(k0 + kk) * DD);
            float4 wB = *(const float4*)(Wc + (size_t)(k0 + kk) * DD + 4);
#pragma unroll
            for (int i = 0; i < 8; i++) {
                float av = (kk == 0) ? a[i].x : (kk == 1) ? a[i].y
                         : (kk == 2) ? a[i].z : a[i].w;
                acc[i][0] = fmaf(av, wA.x, acc[i][0]);
                acc[i][1] = fmaf(av, wA.y, acc[i][1]);
                acc[i][2] = fmaf(av, wA.z, acc[i][2]);
                acc[i][3] = fmaf(av, wA.w, acc[i][3]);
                acc[i][4] = fmaf(av, wB.x, acc[i][4]);
                acc[i][5] = fmaf(av, wB.y, acc[i][5]);
                acc[i][6] = fmaf(av, wB.z, acc[i][6]);
                acc[i][7] = fmaf(av, wB.w, acc[i][7]);
            }
        }
    }

    // bias + relu + write (+ per-column partial stats)
    float4 bA = *(const float4*)&bias[c * 8];
    float4 bB = *(const float4*)&bias[c * 8 + 4];
    float bb[8] = {bA.x, bA.y, bA.z, bA.w, bB.x, bB.y, bB.z, bB.w};

    float csum[8], csq[8];
#pragma unroll
    for (int j = 0; j < 8; j++) { csum[j] = 0.f; csq[j] = 0.f; }

#pragma unroll
    for (int i = 0; i < 8; i++) {
        size_t row = (size_t)(row0 + r * 8 + i);
        float o[8];
#pragma unroll
        for (int j = 0; j < 8; j++) {
            float v = acc[i][j] + bb[j];
            v = v > 0.0f ? v : 0.0f;
            o[j] = v;
            if (STATS) { csum[j] += v; csq[j] += v * v; }
        }
        *(float4*)&Hout[row * DD + c * 8]     = make_float4(o[0], o[1], o[2], o[3]);
        *(float4*)&Hout[row * DD + c * 8 + 4] = make_float4(o[4], o[5], o[6], o[7]);
    }

    if (STATS) {
        __syncthreads();                 // done reading lds; reuse for reduce
        float* redsum = lds;             // [4][512]
        float* redsq  = lds + 2048;      // [4][512]
#pragma unroll
        for (int j = 0; j < 8; j++) {
            redsum[r * DD + c * 8 + j] = csum[j];
            redsq [r * DD + c * 8 + j] = csq[j];
        }
        __syncthreads();
        if (r == 0) {
#pragma unroll
            for (int j = 0; j < 8; j++) {
                int col = c * 8 + j;
                float s = redsum[col] + redsum[DD + col] + redsum[2 * DD + col] + redsum[3 * DD + col];
                float q = redsq [col] + redsq [DD + col] + redsq [2 * DD + col] + redsq [3 * DD + col];
                atomicAdd(&stats[col], s);
                atomicAdd(&stats[DD + col], q);
            }
        }
    }
}

// ---------------------------------------------------------------------------
// pooling: P[g,j] = (sum_{n in g} H[n,j]) * s4[j] + cnt_g * t4[j]
// grid (GG, 4), block 128: block (g, cc) owns cols cc*128..cc*128+127
// ---------------------------------------------------------------------------
__global__ void pool_k(const float* __restrict__ H, const int* __restrict__ starts,
                       const float* __restrict__ s4, const float* __restrict__ t4,
                       float* __restrict__ P) {
    int g = blockIdx.x;
    int j = blockIdx.y * 128 + threadIdx.x;
    int n0 = starts[g], n1 = starts[g + 1];
    float acc = 0.f;
    for (int n = n0; n < n1; n++) acc += H[(size_t)n * DD + j];
    P[g * DD + j] = acc * s4[j] + (float)(n1 - n0) * t4[j];
}

// ---------------------------------------------------------------------------
// head: per-graph  prelu(P@fc1+b) -> sigmoid(@fc2+b) -> @fc3+b
// one block (256 threads) per graph
// ---------------------------------------------------------------------------
__global__ __launch_bounds__(256)
void head_k(const float* __restrict__ P,
            const float* __restrict__ fc1_w, const float* __restrict__ fc1_b,
            const float* __restrict__ fc2_w, const float* __restrict__ fc2_b,
            const float* __restrict__ fc3_w, const float* __restrict__ fc3_b,
            const float* __restrict__ a3, float* __restrict__ out) {
    __shared__ float p[DD], y1[DD], y2[DD / 2];
    int g = blockIdx.x, t = threadIdx.x;
    p[t]       = P[g * DD + t];
    p[t + 256] = P[g * DD + t + 256];
    __syncthreads();
    float alpha = a3[0];

    // fc1 (512x512) + PReLU ; thread handles cols t and t+256
    float acc0 = fc1_b[t], acc1 = fc1_b[t + 256];
    for (int k = 0; k < DD; k++) {
        float pv = p[k];
        acc0 = fmaf(pv, fc1_w[(size_t)k * DD + t], acc0);
        acc1 = fmaf(pv, fc1_w[(size_t)k * DD + t + 256], acc1);
    }
    y1[t]       = acc0 >= 0.f ? acc0 : alpha * acc0;
    y1[t + 256] = acc1 >= 0.f ? acc1 : alpha * acc1;
    __syncthreads();

    // fc2 (512x256) + sigmoid ; thread handles col t
    float acc = fc2_b[t];
    for (int k = 0; k < DD; k++) acc = fmaf(y1[k], fc2_w[(size_t)k * (DD / 2) + t], acc);
    y2[t] = 1.0f / (1.0f + expf(-acc));
    __syncthreads();

    // fc3 (256x10)
    if (t < CC) {
        float a = fc3_b[t];
        for (int k = 0; k < DD / 2; k++) a = fmaf(y2[k], fc3_w[(size_t)k * CC + t], a);
        out[g * CC + t] = a;
    }
}

// ---------------------------------------------------------------------------
// launch
// ---------------------------------------------------------------------------
extern "C" void kernel_launch(void* const* d_in, const int* in_sizes, int n_in,
                              void* d_out, int out_size, void* d_ws, size_t ws_size,
                              hipStream_t stream) {
    const float* x     = (const float*)d_in[0];
    /* d_in[1] edge_index: unused (ChebConv K=1 == linear) */
    const int*   batch = (const int*)d_in[2];
    const float* bn1_g = (const float*)d_in[3];
    const float* bn1_b = (const float*)d_in[4];
    const float* w0    = (const float*)d_in[5];
    const float* b0    = (const float*)d_in[6];
    const float* w1    = (const float*)d_in[7];
    const float* bb1   = (const float*)d_in[8];
    const float* w2    = (const float*)d_in[9];
    const float* bb2   = (const float*)d_in[10];
    const float* w3    = (const float*)d_in[11];
    const float* bb3   = (const float*)d_in[12];
    const float* bn3_g = (const float*)d_in[13];
    const float* bn3_b = (const float*)d_in[14];
    const float* a3    = (const float*)d_in[15];
    const float* fc1_w = (const float*)d_in[16];
    const float* fc1_b = (const float*)d_in[17];
    const float* fc2_w = (const float*)d_in[18];
    const float* fc2_b = (const float*)d_in[19];
    const float* fc3_w = (const float*)d_in[20];
    const float* fc3_b = (const float*)d_in[21];
    float* out = (float*)d_out;

    // workspace layout (floats); total ~206.3 MB
    float* ws = (float*)d_ws;
    size_t off = 0;
    float* H      = ws + off; off += (size_t)NN * DD;       // 51,200,000
    float* stats  = ws + off; off += 3328;                  // x(256) + 3 layers (1024 each)
    float* statsX = stats;
    float* stats2 = stats + 256;
    float* stats3 = stats + 1280;
    float* stats4 = stats + 2304;
    float* s1 = ws + off; off += 128;
    float* t1 = ws + off; off += 128;
    float* s2 = ws + off; off += 512;
    float* t2 = ws + off; off += 512;
    float* s3 = ws + off; off += 512;
    float* t3 = ws + off; off += 512;
    float* s4 = ws + off; off += 512;
    float* t4 = ws + off; off += 512;
    float* W0p = ws + off; off += (size_t)INF * DD;         // 65,536
    float* b0p = ws + off; off += 512;
    float* Wp  = ws + off; off += (size_t)DD * DD;          // 262,144
    float* bp  = ws + off; off += 512;
    float* P   = ws + off; off += (size_t)GG * DD;          // 32,768
    int*   starts = (int*)(ws + off); off += 128;

    (void)in_sizes; (void)n_in; (void)out_size; (void)ws_size;

    // 1) zero stat accumulators (ws is poisoned 0xAA each launch)
    zero_k<<<(3328 + 255) / 256, 256, 0, stream>>>(stats, 3328);
    // 2) graph segment boundaries (batch is sorted)
    bounds_k<<<1, 128, 0, stream>>>(batch, starts);
    // 3) BN1 stats over x
    colstats_x<<<512, 128, 0, stream>>>(x, statsX);
    // 4) fold BN1 into layer0 weights:  W0' = diag(s1)@w0, b0' = b0 + t1@w0
    prep_st<<<1, 128, 0, stream>>>(statsX, 128, bn1_g, bn1_b, s1, t1);
    fold_w<<<(INF * DD + 255) / 256, 256, 0, stream>>>(s1, w0, W0p, INF);
    fold_b<<<2, 256, 0, stream>>>(t1, w0, b0, b0p, INF);
    // 5) layer0: H = relu(x @ W0' + b0')        (no BN after)
    gemm_rb<INF, false><<<NN / 32, 256, 0, stream>>>(x, W0p, b0p, H, nullptr);
    // 6) layer1: H = relu(H @ w1 + bb1), collect stats for BN
    gemm_rb<DD, true><<<NN / 32, 256, 0, stream>>>(H, w1, bb1, H, stats2);
    // 7) layer2: fold BN(stats2) into w2, then H = relu(H @ W2' + b2') + stats
    prep_st<<<2, 256, 0, stream>>>(stats2, 512, bn3_g, bn3_b, s2, t2);
    fold_w<<<(DD * DD + 255) / 256, 256, 0, stream>>>(s2, w2, Wp, DD);
    fold_b<<<2, 256, 0, stream>>>(t2, w2, bb2, bp, DD);
    gemm_rb<DD, true><<<NN / 32, 256, 0, stream>>>(H, Wp, bp, H, stats3);
    // 8) layer3: same with stats3 / w3
    prep_st<<<2, 256, 0, stream>>>(stats3, 512, bn3_g, bn3_b, s3, t3);
    fold_w<<<(DD * DD + 255) / 256, 256, 0, stream>>>(s3, w3, Wp, DD);
    fold_b<<<2, 256, 0, stream>>>(t3, w3, bb3, bp, DD);
    gemm_rb<DD, true><<<NN / 32, 256, 0, stream>>>(H, Wp, bp, H, stats4);
    // 9) final BN folded into pooling: P = segsum(H)*s4 + cnt*t4
    prep_st<<<2, 256, 0, stream>>>(stats4, 512, bn3_g, bn3_b, s4, t4);
    pool_k<<<dim3(GG, 4), 128, 0, stream>>>(H, starts, s4, t4, P);
    // 10) head
    head_k<<<GG, 256, 0, stream>>>(P, fc1_w, fc1_b, fc2_w, fc2_b, fc3_w, fc3_b, a3, out);
}

// Round 2
// 1396.177 us; speedup vs baseline: 2.8627x; 2.8627x over previous
//
#include <hip/hip_runtime.h>
#include <math.h>

#define NN 100000   // nodes
#define INF 128     // input features
#define DD  512     // hidden dim
#define GG  64      // graphs
#define CC  10      // classes

typedef __bf16 bf16;
typedef __bf16 bf16x8 __attribute__((ext_vector_type(8)));
typedef __bf16 bf16x4 __attribute__((ext_vector_type(4)));
typedef float  f32x4  __attribute__((ext_vector_type(4)));
typedef unsigned int u32x4 __attribute__((ext_vector_type(4)));

// ---------------------------------------------------------------------------
// small utility kernels
// ---------------------------------------------------------------------------

__global__ void zero_k(float* __restrict__ p, int n) {
    int i = blockIdx.x * blockDim.x + threadIdx.x;
    if (i < n) p[i] = 0.0f;
}

__global__ void bounds_k(const int* __restrict__ batch, int* __restrict__ starts) {
    int g = threadIdx.x;
    if (g <= GG) {
        int lo = 0, hi = NN;
        while (lo < hi) {
            int mid = (lo + hi) >> 1;
            if (batch[mid] < g) lo = mid + 1; else hi = mid;
        }
        starts[g] = lo;
    }
}

// exact fp32 column stats of x (NN x 128)
__global__ void colstats_x(const float* __restrict__ x, float* __restrict__ stats) {
    int col = threadIdx.x; // 128
    float s = 0.f, q = 0.f;
    for (int row = blockIdx.x; row < NN; row += gridDim.x) {
        float v = x[(size_t)row * INF + col];
        s += v; q += v * v;
    }
    atomicAdd(&stats[col], s);
    atomicAdd(&stats[INF + col], q);
}

// column stats of bf16 H (M x 512): stats[0..511]=sum, [512..1023]=sumsq
__global__ __launch_bounds__(256)
void colstats_h(const bf16* __restrict__ H, float* __restrict__ stats, int M) {
    __shared__ float red[8][DD];   // [0..3]=sum per row-group, [4..7]=sumsq
    int t = threadIdx.x;
    int rg = t >> 6;               // 0..3
    int c8 = (t & 63) * 8;         // col base
    float s[8], q[8];
#pragma unroll
    for (int j = 0; j < 8; j++) { s[j] = 0.f; q[j] = 0.f; }
    for (int row = blockIdx.x * 4 + rg; row < M; row += gridDim.x * 4) {
        bf16x8 v = *(const bf16x8*)&H[(size_t)row * DD + c8];
#pragma unroll
        for (int j = 0; j < 8; j++) { float f = (float)v[j]; s[j] += f; q[j] += f * f; }
    }
#pragma unroll
    for (int j = 0; j < 8; j++) { red[rg][c8 + j] = s[j]; red[4 + rg][c8 + j] = q[j]; }
    __syncthreads();
    if (rg == 0) {
#pragma unroll
        for (int j = 0; j < 8; j++) {
            int col = c8 + j;
            atomicAdd(&stats[col],      red[0][col] + red[1][col] + red[2][col] + red[3][col]);
            atomicAdd(&stats[DD + col], red[4][col] + red[5][col] + red[6][col] + red[7][col]);
        }
    }
}

// s = gamma * rsqrt(var+eps); t = beta - mean*s   (biased var)
__global__ void prep_st(const float* __restrict__ stats, int K,
                        const float* __restrict__ gamma, const float* __restrict__ beta,
                        float* __restrict__ s, float* __restrict__ t) {
    int j = blockIdx.x * blockDim.x + threadIdx.x;
    if (j < K) {
        const float invN = 1.0f / (float)NN;
        float mean = stats[j] * invN;
        float var  = stats[K + j] * invN - mean * mean;
        float sv   = gamma[j] * rsqrtf(var + 1e-5f);
        s[j] = sv;
        t[j] = beta[j] - mean * sv;
    }
}

// Wt[j][k] = bf16( (s?s[k]:1) * W[k][j] )  — fold + transpose + cast. W is K x 512.
__global__ void fold_wt(const float* __restrict__ s, const float* __restrict__ W,
                        bf16* __restrict__ Wt, int K) {
    int id = blockIdx.x * 256 + threadIdx.x;
    if (id < DD * K) {
        int j = id / K, k = id - j * K;
        float sv = s ? s[k] : 1.0f;
        Wt[(size_t)j * K + k] = (bf16)(sv * W[(size_t)k * DD + j]);
    }
}

// bp[j] = b[j] + sum_k t[k]*W[k][j]   (fp32, exact)
__global__ void fold_b(const float* __restrict__ t, const float* __restrict__ W,
                       const float* __restrict__ b, float* __restrict__ bp, int K) {
    int j = blockIdx.x * blockDim.x + threadIdx.x;
    if (j < DD) {
        float acc = b[j];
        for (int k = 0; k < K; k++) acc += t[k] * W[(size_t)k * DD + j];
        bp[j] = acc;
    }
}

// x (fp32) -> bf16
__global__ void cvt_x(const float* __restrict__ x, bf16* __restrict__ xb, int n) {
    int i = (blockIdx.x * blockDim.x + threadIdx.x) * 4;
    if (i < n) {
        float4 v = *(const float4*)&x[i];
        xb[i]     = (bf16)v.x;
        xb[i + 1] = (bf16)v.y;
        xb[i + 2] = (bf16)v.z;
        xb[i + 3] = (bf16)v.w;
    }
}

// ---------------------------------------------------------------------------
// MFMA GEMM: H[r, col0..col0+127] = relu(A[r,:] @ Wt^T + bias)
//   A : M x K bf16 row-major;  Wt : 512 x K bf16 (pre-transposed weights)
// grid (ceil(M/128), 4), block 256 = 4 waves; wave (wr,wc) owns 64x64 via
// 4x4 fragments of mfma_f32_16x16x32_bf16.
// LDS rows padded to 72 bf16 (144 B): frag ds_read_b128 spreads over all
// 8 bank-quads -> conflict-free. A/B frags use the same phi(g,i)=g*8+i
// k-mapping, so correctness is independent of HW's internal k order.
// C/D layout (HW-verified): col=lane&15, row=(lane>>4)*4+reg.
// ---------------------------------------------------------------------------
template <int K>
__global__ __launch_bounds__(256, 2)
void gemm_mfma(const bf16* __restrict__ A, const bf16* __restrict__ Wt,
               const float* __restrict__ bias, bf16* __restrict__ H, int M) {
    __shared__ bf16 As[128][72];
    __shared__ bf16 Bs[128][72];
    const int t  = threadIdx.x;
    const int l  = t & 63;
    const int w  = t >> 6;
    const int wr = w >> 1, wc = w & 1;
    const int row0 = blockIdx.x * 128;
    const int col0 = blockIdx.y * 128;
    const int sr = t >> 1;     // staging row 0..127
    const int sh = t & 1;      // staging half (32 k each)

    f32x4 acc[4][4];
#pragma unroll
    for (int m = 0; m < 4; m++)
#pragma unroll
        for (int n = 0; n < 4; n++) acc[m][n] = (f32x4){0.f, 0.f, 0.f, 0.f};

    int ar = row0 + sr; if (ar >= M) ar = M - 1;   // clamp; OOB rows unused
    const bf16* Asrc = A  + (size_t)ar * K + sh * 32;
    const bf16* Bsrc = Wt + (size_t)(col0 + sr) * K + sh * 32;

#pragma unroll 1
    for (int k0 = 0; k0 < K; k0 += 64) {
#pragma unroll
        for (int c = 0; c < 4; c++) {
            *(u32x4*)&As[sr][sh * 32 + c * 8] = *(const u32x4*)(Asrc + k0 + c * 8);
            *(u32x4*)&Bs[sr][sh * 32 + c * 8] = *(const u32x4*)(Bsrc + k0 + c * 8);
        }
        __syncthreads();
#pragma unroll
        for (int ks = 0; ks < 2; ks++) {
            bf16x8 af[4], bf[4];
#pragma unroll
            for (int m = 0; m < 4; m++)
                af[m] = *(const bf16x8*)&As[wr * 64 + m * 16 + (l & 15)][ks * 32 + (l >> 4) * 8];
#pragma unroll
            for (int n = 0; n < 4; n++)
                bf[n] = *(const bf16x8*)&Bs[wc * 64 + n * 16 + (l & 15)][ks * 32 + (l >> 4) * 8];
#pragma unroll
            for (int m = 0; m < 4; m++)
#pragma unroll
                for (int n = 0; n < 4; n++)
                    acc[m][n] = __builtin_amdgcn_mfma_f32_16x16x32_bf16(af[m], bf[n], acc[m][n], 0, 0, 0);
        }
        __syncthreads();
    }

    // epilogue: bias + relu + bf16 store (guard tail rows)
#pragma unroll
    for (int n = 0; n < 4; n++) {
        int col = col0 + wc * 64 + n * 16 + (l & 15);
        float bv = bias[col];
#pragma unroll
        for (int m = 0; m < 4; m++) {
#pragma unroll
            for (int q = 0; q < 4; q++) {
                int grow = row0 + wr * 64 + m * 16 + (l >> 4) * 4 + q;
                if (grow < M) {
                    float v = acc[m][n][q] + bv;
                    v = v > 0.f ? v : 0.f;
                    H[(size_t)grow * DD + col] = (bf16)v;
                }
            }
        }
    }
}

// ---------------------------------------------------------------------------
// pooling: P[g,j] = segsum(H)[g,j] * s4[j] + cnt_g * t4[j]   (H bf16)
// grid GG, block 128; thread owns 4 cols
// ---------------------------------------------------------------------------
__global__ __launch_bounds__(128)
void pool_k(const bf16* __restrict__ H, const int* __restrict__ starts,
            const float* __restrict__ s4, const float* __restrict__ t4,
            float* __restrict__ P) {
    int g  = blockIdx.x;
    int c4 = threadIdx.x * 4;
    int n0 = starts[g], n1 = starts[g + 1];
    float a0 = 0.f, a1 = 0.f, a2 = 0.f, a3 = 0.f;
#pragma unroll 4
    for (int n = n0; n < n1; n++) {
        bf16x4 v = *(const bf16x4*)&H[(size_t)n * DD + c4];
        a0 += (float)v[0]; a1 += (float)v[1]; a2 += (float)v[2]; a3 += (float)v[3];
    }
    float cnt = (float)(n1 - n0);
    float4 sv = *(const float4*)&s4[c4];
    float4 tv = *(const float4*)&t4[c4];
    *(float4*)&P[g * DD + c4] = make_float4(a0 * sv.x + cnt * tv.x, a1 * sv.y + cnt * tv.y,
                                            a2 * sv.z + cnt * tv.z, a3 * sv.w + cnt * tv.w);
}

// ---------------------------------------------------------------------------
// head: per-graph  prelu(P@fc1+b) -> sigmoid(@fc2+b) -> @fc3+b  (fp32)
// ---------------------------------------------------------------------------
__global__ __launch_bounds__(256)
void head_k(const float* __restrict__ P,
            const float* __restrict__ fc1_w, const float* __restrict__ fc1_b,
            const float* __restrict__ fc2_w, const float* __restrict__ fc2_b,
            const float* __restrict__ fc3_w, const float* __restrict__ fc3_b,
            const float* __restrict__ a3, float* __restrict__ out) {
    __shared__ float p[DD], y1[DD], y2[DD / 2];
    int g = blockIdx.x, t = threadIdx.x;
    p[t]       = P[g * DD + t];
    p[t + 256] = P[g * DD + t + 256];
    __syncthreads();
    float alpha = a3[0];

    float acc0 = fc1_b[t], acc1 = fc1_b[t + 256];
    for (int k = 0; k < DD; k++) {
        float pv = p[k];
        acc0 = fmaf(pv, fc1_w[(size_t)k * DD + t], acc0);
        acc1 = fmaf(pv, fc1_w[(size_t)k * DD + t + 256], acc1);
    }
    y1[t]       = acc0 >= 0.f ? acc0 : alpha * acc0;
    y1[t + 256] = acc1 >= 0.f ? acc1 : alpha * acc1;
    __syncthreads();

    float acc = fc2_b[t];
    for (int k = 0; k < DD; k++) acc = fmaf(y1[k], fc2_w[(size_t)k * (DD / 2) + t], acc);
    y2[t] = 1.0f / (1.0f + expf(-acc));
    __syncthreads();

    if (t < CC) {
        float a = fc3_b[t];
        for (int k = 0; k < DD / 2; k++) a = fmaf(y2[k], fc3_w[(size_t)k * CC + t], a);
        out[g * CC + t] = a;
    }
}

// ---------------------------------------------------------------------------
// launch
// ---------------------------------------------------------------------------
extern "C" void kernel_launch(void* const* d_in, const int* in_sizes, int n_in,
                              void* d_out, int out_size, void* d_ws, size_t ws_size,
                              hipStream_t stream) {
    const float* x     = (const float*)d_in[0];
    /* d_in[1] edge_index: unused (ChebConv K=1 == linear) */
    const int*   batch = (const int*)d_in[2];
    const float* bn1_g = (const float*)d_in[3];
    const float* bn1_b = (const float*)d_in[4];
    const float* w0    = (const float*)d_in[5];
    const float* b0    = (const float*)d_in[6];
    const float* w1    = (const float*)d_in[7];
    const float* bb1   = (const float*)d_in[8];
    const float* w2    = (const float*)d_in[9];
    const float* bb2   = (const float*)d_in[10];
    const float* w3    = (const float*)d_in[11];
    const float* bb3   = (const float*)d_in[12];
    const float* bn3_g = (const float*)d_in[13];
    const float* bn3_b = (const float*)d_in[14];
    const float* a3    = (const float*)d_in[15];
    const float* fc1_w = (const float*)d_in[16];
    const float* fc1_b = (const float*)d_in[17];
    const float* fc2_w = (const float*)d_in[18];
    const float* fc2_b = (const float*)d_in[19];
    const float* fc3_w = (const float*)d_in[20];
    const float* fc3_b = (const float*)d_in[21];
    float* out = (float*)d_out;

    // ---- workspace layout (bytes, 16B-aligned chunks) ----
    char* base = (char*)d_ws;
    const size_t HBYTES = (size_t)NN * DD * 2;       // 102,400,000
    bf16* Ha = (bf16*)base;
    bf16* Hb = (bf16*)(base + HBYTES);
    bf16* Xb = Hb;                                   // alias: dead after layer0
    bf16* Wt = (bf16*)(base + 2 * HBYTES);           // 512*512*2 = 524,288
    float* f = (float*)(base + 2 * HBYTES + 524288);
    size_t off = 0;
    float* stats  = f + off; off += 3328;            // x(256) + 3 layers (1024 each)
    float* statsX = stats;
    float* stats2 = stats + 256;
    float* stats3 = stats + 1280;
    float* stats4 = stats + 2304;
    float* s1 = f + off; off += 128;
    float* t1 = f + off; off += 128;
    float* s2 = f + off; off += 512;
    float* t2 = f + off; off += 512;
    float* s3 = f + off; off += 512;
    float* t3 = f + off; off += 512;
    float* s4 = f + off; off += 512;
    float* t4 = f + off; off += 512;
    float* b0p = f + off; off += 512;
    float* bp  = f + off; off += 512;
    float* P   = f + off; off += (size_t)GG * DD;    // 32,768
    int*   starts = (int*)(f + off); off += 128;

    (void)in_sizes; (void)n_in; (void)out_size; (void)ws_size;

    const dim3 ggrid(( NN + 127) / 128, 4);

    // stat accumulators must start at zero (ws is poisoned 0xAA)
    zero_k<<<(3328 + 255) / 256, 256, 0, stream>>>(stats, 3328);
    bounds_k<<<1, 128, 0, stream>>>(batch, starts);

    // BN1 (exact fp32 stats on x), fold into layer0
    colstats_x<<<512, 128, 0, stream>>>(x, statsX);
    prep_st<<<1, 128, 0, stream>>>(statsX, 128, bn1_g, bn1_b, s1, t1);
    cvt_x<<<(NN * INF / 4 + 255) / 256, 256, 0, stream>>>(x, Xb, NN * INF);
    fold_wt<<<(DD * INF + 255) / 256, 256, 0, stream>>>(s1, w0, Wt, INF);
    fold_b<<<2, 256, 0, stream>>>(t1, w0, b0, b0p, INF);
    // layer0: Ha = relu(Xb @ W0' + b0')
    gemm_mfma<INF><<<ggrid, 256, 0, stream>>>(Xb, Wt, b0p, Ha, NN);

    // layer1: Hb = relu(Ha @ w1 + bb1); stats for BN
    fold_wt<<<(DD * DD + 255) / 256, 256, 0, stream>>>(nullptr, w1, Wt, DD);
    gemm_mfma<DD><<<ggrid, 256, 0, stream>>>(Ha, Wt, bb1, Hb, NN);
    colstats_h<<<512, 256, 0, stream>>>(Hb, stats2, NN);

    // layer2: fold BN(stats2) into w2; Ha = relu(Hb @ W2' + b2')
    prep_st<<<2, 256, 0, stream>>>(stats2, 512, bn3_g, bn3_b, s2, t2);
    fold_wt<<<(DD * DD + 255) / 256, 256, 0, stream>>>(s2, w2, Wt, DD);
    fold_b<<<2, 256, 0, stream>>>(t2, w2, bb2, bp, DD);
    gemm_mfma<DD><<<ggrid, 256, 0, stream>>>(Hb, Wt, bp, Ha, NN);
    colstats_h<<<512, 256, 0, stream>>>(Ha, stats3, NN);

    // layer3: fold BN(stats3) into w3; Hb = relu(Ha @ W3' + b3')
    prep_st<<<2, 256, 0, stream>>>(stats3, 512, bn3_g, bn3_b, s3, t3);
    fold_wt<<<(DD * DD + 255) / 256, 256, 0, stream>>>(s3, w3, Wt, DD);
    fold_b<<<2, 256, 0, stream>>>(t3, w3, bb3, bp, DD);
    gemm_mfma<DD><<<ggrid, 256, 0, stream>>>(Ha, Wt, bp, Hb, NN);
    colstats_h<<<512, 256, 0, stream>>>(Hb, stats4, NN);

    // final BN folded into pooling
    prep_st<<<2, 256, 0, stream>>>(stats4, 512, bn3_g, bn3_b, s4, t4);
    pool_k<<<GG, 128, 0, stream>>>(Hb, starts, s4, t4, P);
    head_k<<<GG, 256, 0, stream>>>(P, fc1_w, fc1_b, fc2_w, fc2_b, fc3_w, fc3_b, a3, out);
}

// Round 7
// 1016.001 us; speedup vs baseline: 3.9339x; 1.3742x over previous
//
#include <hip/hip_runtime.h>
#include <math.h>

#define NN 100000   // nodes
#define INF 128     // input features
#define DD  512     // hidden dim
#define GG  64      // graphs
#define CC  10      // classes

typedef __bf16 bf16;
typedef __bf16 bf16x8 __attribute__((ext_vector_type(8)));
typedef __bf16 bf16x4 __attribute__((ext_vector_type(4)));
typedef float  f32x4  __attribute__((ext_vector_type(4)));
typedef unsigned int u32x4 __attribute__((ext_vector_type(4)));

// ---------------------------------------------------------------------------
// small utility kernels
// ---------------------------------------------------------------------------

__global__ void zero_k(float* __restrict__ p, int n) {
    int i = blockIdx.x * blockDim.x + threadIdx.x;
    if (i < n) p[i] = 0.0f;
}

__global__ void bounds_k(const int* __restrict__ batch, int* __restrict__ starts) {
    int g = threadIdx.x;
    if (g <= GG) {
        int lo = 0, hi = NN;
        while (lo < hi) {
            int mid = (lo + hi) >> 1;
            if (batch[mid] < g) lo = mid + 1; else hi = mid;
        }
        starts[g] = lo;
    }
}

// fused: exact fp32 column stats of x (NN x 128) + bf16 cast (one read of x)
__global__ void colstats_cvt(const float* __restrict__ x, bf16* __restrict__ xb,
                             float* __restrict__ stats) {
    int col = threadIdx.x; // 128
    float s = 0.f, q = 0.f;
    for (int row = blockIdx.x; row < NN; row += gridDim.x) {
        float v = x[(size_t)row * INF + col];
        s += v; q += v * v;
        xb[(size_t)row * INF + col] = (bf16)v;
    }
    atomicAdd(&stats[col], s);
    atomicAdd(&stats[INF + col], q);
}

// s = gamma * rsqrt(var+eps); t = beta - mean*s   (biased var)
__global__ void prep_st(const float* __restrict__ stats, int K,
                        const float* __restrict__ gamma, const float* __restrict__ beta,
                        float* __restrict__ s, float* __restrict__ t) {
    int j = blockIdx.x * blockDim.x + threadIdx.x;
    if (j < K) {
        const float invN = 1.0f / (float)NN;
        float mean = stats[j] * invN;
        float var  = stats[K + j] * invN - mean * mean;
        float sv   = gamma[j] * rsqrtf(var + 1e-5f);
        s[j] = sv;
        t[j] = beta[j] - mean * sv;
    }
}

// Wt[j][k] = bf16( (s?s[k]:1) * W[k][j] )  — fold + transpose + cast. W is K x 512.
__global__ void fold_wt(const float* __restrict__ s, const float* __restrict__ W,
                        bf16* __restrict__ Wt, int K) {
    int id = blockIdx.x * 256 + threadIdx.x;
    if (id < DD * K) {
        int j = id / K, k = id - j * K;
        float sv = s ? s[k] : 1.0f;
        Wt[(size_t)j * K + k] = (bf16)(sv * W[(size_t)k * DD + j]);
    }
}

// bp[j] = b[j] + sum_k t[k]*W[k][j]   (fp32, exact)
__global__ void fold_b(const float* __restrict__ t, const float* __restrict__ W,
                       const float* __restrict__ b, float* __restrict__ bp, int K) {
    int j = blockIdx.x * blockDim.x + threadIdx.x;
    if (j < DD) {
        float acc = b[j];
        for (int k = 0; k < K; k++) acc += t[k] * W[(size_t)k * DD + j];
        bp[j] = acc;
    }
}

// ---------------------------------------------------------------------------
// MFMA GEMM: H[r, col0..col0+127] = relu(A[r,:] @ Wt^T + bias)
//   A : M x K bf16 row-major;  Wt : 512 x K bf16 (pre-transposed weights)
// grid (ceil(M/128), 4), block 256 = 4 waves; wave (wr,wc) owns 64x64 via
// 4x4 fragments of mfma_f32_16x16x32_bf16.
// LDS rows padded to 72 bf16 (144 B) -> conflict-free frag ds_read_b128.
// A/B frags use the same phi(g,i)=g*8+i k-mapping (k-order-agnostic).
// C/D layout (HW-verified): col=lane&15, row=(lane>>4)*4+reg.
// STATS: fused per-column sum/sumsq of the relu'd output -> stats[0..511]/
// stats[512..1023] via shfl_xor(16/32) + LDS cross-wave combine + atomics.
// ---------------------------------------------------------------------------
template <int K, bool STATS>
__global__ __launch_bounds__(256, 2)
void gemm_mfma(const bf16* __restrict__ A, const bf16* __restrict__ Wt,
               const float* __restrict__ bias, bf16* __restrict__ H, int M,
               float* __restrict__ stats) {
    __shared__ bf16 As[128][72];
    __shared__ bf16 Bs[128][72];
    const int t  = threadIdx.x;
    const int l  = t & 63;
    const int w  = t >> 6;
    const int wr = w >> 1, wc = w & 1;
    const int row0 = blockIdx.x * 128;
    const int col0 = blockIdx.y * 128;
    const int sr = t >> 1;     // staging row 0..127
    const int sh = t & 1;      // staging half (32 k each)

    f32x4 acc[4][4];
#pragma unroll
    for (int m = 0; m < 4; m++)
#pragma unroll
        for (int n = 0; n < 4; n++) acc[m][n] = (f32x4){0.f, 0.f, 0.f, 0.f};

    int ar = row0 + sr; if (ar >= M) ar = M - 1;   // clamp; OOB rows unused
    const bf16* Asrc = A  + (size_t)ar * K + sh * 32;
    const bf16* Bsrc = Wt + (size_t)(col0 + sr) * K + sh * 32;

#pragma unroll 1
    for (int k0 = 0; k0 < K; k0 += 64) {
#pragma unroll
        for (int c = 0; c < 4; c++) {
            *(u32x4*)&As[sr][sh * 32 + c * 8] = *(const u32x4*)(Asrc + k0 + c * 8);
            *(u32x4*)&Bs[sr][sh * 32 + c * 8] = *(const u32x4*)(Bsrc + k0 + c * 8);
        }
        __syncthreads();
#pragma unroll
        for (int ks = 0; ks < 2; ks++) {
            bf16x8 af[4], bfr[4];
#pragma unroll
            for (int m = 0; m < 4; m++)
                af[m] = *(const bf16x8*)&As[wr * 64 + m * 16 + (l & 15)][ks * 32 + (l >> 4) * 8];
#pragma unroll
            for (int n = 0; n < 4; n++)
                bfr[n] = *(const bf16x8*)&Bs[wc * 64 + n * 16 + (l & 15)][ks * 32 + (l >> 4) * 8];
#pragma unroll
            for (int m = 0; m < 4; m++)
#pragma unroll
                for (int n = 0; n < 4; n++)
                    acc[m][n] = __builtin_amdgcn_mfma_f32_16x16x32_bf16(af[m], bfr[n], acc[m][n], 0, 0, 0);
        }
        __syncthreads();
    }

    // epilogue: bias + relu + bf16 store (+ fused column stats)
    float csumA[4], csqA[4];
#pragma unroll
    for (int n = 0; n < 4; n++) {
        int col = col0 + wc * 64 + n * 16 + (l & 15);
        float bv = bias[col];
        float cs = 0.f, cq = 0.f;
#pragma unroll
        for (int m = 0; m < 4; m++) {
#pragma unroll
            for (int q = 0; q < 4; q++) {
                int grow = row0 + wr * 64 + m * 16 + (l >> 4) * 4 + q;
                if (grow < M) {
                    float v = acc[m][n][q] + bv;
                    v = v > 0.f ? v : 0.f;
                    H[(size_t)grow * DD + col] = (bf16)v;
                    if (STATS) { cs += v; cq += v * v; }
                }
            }
        }
        csumA[n] = cs; csqA[n] = cq;
    }

    if (STATS) {
        float* red = (float*)&As[0][0];   // reuse LDS (all waves past final barrier)
#pragma unroll
        for (int n = 0; n < 4; n++) {
            float cs = csumA[n], cq = csqA[n];
            cs += __shfl_xor(cs, 16); cs += __shfl_xor(cs, 32);
            cq += __shfl_xor(cq, 16); cq += __shfl_xor(cq, 32);
            if ((l >> 4) == 0) {                 // lane holds full 64-row wave sum
                int lc = wc * 64 + n * 16 + l;   // 0..127 block-local col
                red[(wr * 128 + lc) * 2 + 0] = cs;
                red[(wr * 128 + lc) * 2 + 1] = cq;
            }
        }
        __syncthreads();
        if (t < 128) {
            float cs = red[t * 2]     + red[(128 + t) * 2];
            float cq = red[t * 2 + 1] + red[(128 + t) * 2 + 1];
            atomicAdd(&stats[col0 + t], cs);
            atomicAdd(&stats[DD + col0 + t], cq);
        }
    }
}

// ---------------------------------------------------------------------------
// parallel segment-sum: R[g][c] += sum over rows of chunk belonging to g
// grid 782 (128-row chunks), block 128 (thread owns 4 cols); flush on
// (uniform) graph change + at chunk end. R must be pre-zeroed.
// ---------------------------------------------------------------------------
__global__ __launch_bounds__(128)
void pool_sum(const bf16* __restrict__ H, const int* __restrict__ batch,
              float* __restrict__ R, int M) {
    int c4 = threadIdx.x * 4;
    int r0 = blockIdx.x * 128;
    int r1 = r0 + 128; if (r1 > M) r1 = M;
    int gprev = batch[r0];
    float a0 = 0.f, a1 = 0.f, a2 = 0.f, a3 = 0.f;
    for (int n = r0; n < r1; n++) {
        int g = batch[n];                      // uniform across block
        if (g != gprev) {
            atomicAdd(&R[(size_t)gprev * DD + c4 + 0], a0);
            atomicAdd(&R[(size_t)gprev * DD + c4 + 1], a1);
            atomicAdd(&R[(size_t)gprev * DD + c4 + 2], a2);
            atomicAdd(&R[(size_t)gprev * DD + c4 + 3], a3);
            a0 = a1 = a2 = a3 = 0.f; gprev = g;
        }
        bf16x4 v = *(const bf16x4*)&H[(size_t)n * DD + c4];
        a0 += (float)v[0]; a1 += (float)v[1]; a2 += (float)v[2]; a3 += (float)v[3];
    }
    atomicAdd(&R[(size_t)gprev * DD + c4 + 0], a0);
    atomicAdd(&R[(size_t)gprev * DD + c4 + 1], a1);
    atomicAdd(&R[(size_t)gprev * DD + c4 + 2], a2);
    atomicAdd(&R[(size_t)gprev * DD + c4 + 3], a3);
}

// P[g][j] = R[g][j]*s4[j] + cnt_g*t4[j]
__global__ __launch_bounds__(512)
void pool_fin(const float* __restrict__ R, const int* __restrict__ starts,
              const float* __restrict__ s4, const float* __restrict__ t4,
              float* __restrict__ P) {
    int g = blockIdx.x, j = threadIdx.x;
    float cnt = (float)(starts[g + 1] - starts[g]);
    P[g * DD + j] = R[(size_t)g * DD + j] * s4[j] + cnt * t4[j];
}

// ---------------------------------------------------------------------------
// head: per-graph  prelu(P@fc1+b) -> sigmoid(@fc2+b) -> @fc3+b  (fp32)
// ---------------------------------------------------------------------------
__global__ __launch_bounds__(256)
void head_k(const float* __restrict__ P,
            const float* __restrict__ fc1_w, const float* __restrict__ fc1_b,
            const float* __restrict__ fc2_w, const float* __restrict__ fc2_b,
            const float* __restrict__ fc3_w, const float* __restrict__ fc3_b,
            const float* __restrict__ a3, float* __restrict__ out) {
    __shared__ float p[DD], y1[DD], y2[DD / 2];
    int g = blockIdx.x, t = threadIdx.x;
    p[t]       = P[g * DD + t];
    p[t + 256] = P[g * DD + t + 256];
    __syncthreads();
    float alpha = a3[0];

    float acc0 = fc1_b[t], acc1 = fc1_b[t + 256];
    for (int k = 0; k < DD; k++) {
        float pv = p[k];
        acc0 = fmaf(pv, fc1_w[(size_t)k * DD + t], acc0);
        acc1 = fmaf(pv, fc1_w[(size_t)k * DD + t + 256], acc1);
    }
    y1[t]       = acc0 >= 0.f ? acc0 : alpha * acc0;
    y1[t + 256] = acc1 >= 0.f ? acc1 : alpha * acc1;
    __syncthreads();

    float acc = fc2_b[t];
    for (int k = 0; k < DD; k++) acc = fmaf(y1[k], fc2_w[(size_t)k * (DD / 2) + t], acc);
    y2[t] = 1.0f / (1.0f + expf(-acc));
    __syncthreads();

    if (t < CC) {
        float a = fc3_b[t];
        for (int k = 0; k < DD / 2; k++) a = fmaf(y2[k], fc3_w[(size_t)k * CC + t], a);
        out[g * CC + t] = a;
    }
}

// ---------------------------------------------------------------------------
// launch
// ---------------------------------------------------------------------------
extern "C" void kernel_launch(void* const* d_in, const int* in_sizes, int n_in,
                              void* d_out, int out_size, void* d_ws, size_t ws_size,
                              hipStream_t stream) {
    const float* x     = (const float*)d_in[0];
    /* d_in[1] edge_index: unused (ChebConv K=1 == linear) */
    const int*   batch = (const int*)d_in[2];
    const float* bn1_g = (const float*)d_in[3];
    const float* bn1_b = (const float*)d_in[4];
    const float* w0    = (const float*)d_in[5];
    const float* b0    = (const float*)d_in[6];
    const float* w1    = (const float*)d_in[7];
    const float* bb1   = (const float*)d_in[8];
    const float* w2    = (const float*)d_in[9];
    const float* bb2   = (const float*)d_in[10];
    const float* w3    = (const float*)d_in[11];
    const float* bb3   = (const float*)d_in[12];
    const float* bn3_g = (const float*)d_in[13];
    const float* bn3_b = (const float*)d_in[14];
    const float* a3    = (const float*)d_in[15];
    const float* fc1_w = (const float*)d_in[16];
    const float* fc1_b = (const float*)d_in[17];
    const float* fc2_w = (const float*)d_in[18];
    const float* fc2_b = (const float*)d_in[19];
    const float* fc3_w = (const float*)d_in[20];
    const float* fc3_b = (const float*)d_in[21];
    float* out = (float*)d_out;

    // ---- workspace layout ----
    char* base = (char*)d_ws;
    const size_t HBYTES = (size_t)NN * DD * 2;       // 102,400,000
    bf16* Ha = (bf16*)base;
    bf16* Hb = (bf16*)(base + HBYTES);
    bf16* Xb = Hb;                                   // alias: dead after layer0
    bf16* Wt = (bf16*)(base + 2 * HBYTES);           // 512*512*2 = 524,288
    float* f = (float*)(base + 2 * HBYTES + 524288);
    size_t off = 0;
    float* stats  = f + off; off += 3328;            // x(256) + 3 layers (1024 each)
    float* R      = f + off; off += (size_t)GG * DD; // 32,768 (zeroed with stats)
    float* statsX = stats;
    float* stats2 = stats + 256;
    float* stats3 = stats + 1280;
    float* stats4 = stats + 2304;
    float* s1 = f + off; off += 128;
    float* t1 = f + off; off += 128;
    float* s2 = f + off; off += 512;
    float* t2 = f + off; off += 512;
    float* s3 = f + off; off += 512;
    float* t3 = f + off; off += 512;
    float* s4 = f + off; off += 512;
    float* t4 = f + off; off += 512;
    float* b0p = f + off; off += 512;
    float* bp  = f + off; off += 512;
    float* P   = f + off; off += (size_t)GG * DD;    // 32,768
    int*   starts = (int*)(f + off); off += 128;

    (void)in_sizes; (void)n_in; (void)out_size; (void)ws_size;

    const dim3 ggrid((NN + 127) / 128, 4);
    const int kZeroCount = 3328 + GG * DD;           // stats + R contiguous

    zero_k<<<(kZeroCount + 255) / 256, 256, 0, stream>>>(stats, kZeroCount);
    bounds_k<<<1, 128, 0, stream>>>(batch, starts);

    // BN1 (exact fp32 stats on x) fused with bf16 cast; fold into layer0
    colstats_cvt<<<512, 128, 0, stream>>>(x, Xb, statsX);
    prep_st<<<1, 128, 0, stream>>>(statsX, 128, bn1_g, bn1_b, s1, t1);
    fold_wt<<<(DD * INF + 255) / 256, 256, 0, stream>>>(s1, w0, Wt, INF);
    fold_b<<<2, 256, 0, stream>>>(t1, w0, b0, b0p, INF);
    // layer0: Ha = relu(Xb @ W0' + b0')
    gemm_mfma<INF, false><<<ggrid, 256, 0, stream>>>(Xb, Wt, b0p, Ha, NN, nullptr);

    // layer1: Hb = relu(Ha @ w1 + bb1) + fused stats2
    fold_wt<<<(DD * DD + 255) / 256, 256, 0, stream>>>(nullptr, w1, Wt, DD);
    gemm_mfma<DD, true><<<ggrid, 256, 0, stream>>>(Ha, Wt, bb1, Hb, NN, stats2);

    // layer2: fold BN(stats2) into w2; Ha = relu(Hb @ W2' + b2') + stats3
    prep_st<<<2, 256, 0, stream>>>(stats2, 512, bn3_g, bn3_b, s2, t2);
    fold_wt<<<(DD * DD + 255) / 256, 256, 0, stream>>>(s2, w2, Wt, DD);
    fold_b<<<2, 256, 0, stream>>>(t2, w2, bb2, bp, DD);
    gemm_mfma<DD, true><<<ggrid, 256, 0, stream>>>(Hb, Wt, bp, Ha, NN, stats3);

    // layer3: fold BN(stats3) into w3; Hb = relu(Ha @ W3' + b3') + stats4
    prep_st<<<2, 256, 0, stream>>>(stats3, 512, bn3_g, bn3_b, s3, t3);
    fold_wt<<<(DD * DD + 255) / 256, 256, 0, stream>>>(s3, w3, Wt, DD);
    fold_b<<<2, 256, 0, stream>>>(t3, w3, bb3, bp, DD);
    gemm_mfma<DD, true><<<ggrid, 256, 0, stream>>>(Ha, Wt, bp, Hb, NN, stats4);

    // pooling: raw segment sums (independent of s4/t4), then BN-folded combine
    pool_sum<<<(NN + 127) / 128, 128, 0, stream>>>(Hb, batch, R, NN);
    prep_st<<<2, 256, 0, stream>>>(stats4, 512, bn3_g, bn3_b, s4, t4);
    pool_fin<<<GG, 512, 0, stream>>>(R, starts, s4, t4, P);
    head_k<<<GG, 256, 0, stream>>>(P, fc1_w, fc1_b, fc2_w, fc2_b, fc3_w, fc3_b, a3, out);
}

// Round 8
// 639.123 us; speedup vs baseline: 6.2536x; 1.5897x over previous
//
#include <hip/hip_runtime.h>
#include <math.h>

#define NN 100000   // nodes
#define INF 128     // input features
#define DD  512     // hidden dim
#define GG  64      // graphs
#define CC  10      // classes

typedef __bf16 bf16;
typedef __bf16 bf16x8 __attribute__((ext_vector_type(8)));
typedef __bf16 bf16x4 __attribute__((ext_vector_type(4)));
typedef float  f32x4  __attribute__((ext_vector_type(4)));
typedef unsigned int u32x4 __attribute__((ext_vector_type(4)));

// ---------------------------------------------------------------------------
// small utility kernels
// ---------------------------------------------------------------------------

__global__ void zero_k(float* __restrict__ p, int n) {
    int i = blockIdx.x * blockDim.x + threadIdx.x;
    if (i < n) p[i] = 0.0f;
}

__global__ void bounds_k(const int* __restrict__ batch, int* __restrict__ starts) {
    int g = threadIdx.x;
    if (g <= GG) {
        int lo = 0, hi = NN;
        while (lo < hi) {
            int mid = (lo + hi) >> 1;
            if (batch[mid] < g) lo = mid + 1; else hi = mid;
        }
        starts[g] = lo;
    }
}

// fused: exact fp32 column stats of x (NN x 128) + bf16 cast, vectorized.
// block 256 = 8 row-lanes x 32 col-quads; float4 read, bf16x4 write.
__global__ __launch_bounds__(256)
void colstats_cvt(const float* __restrict__ x, bf16* __restrict__ xb,
                  float* __restrict__ stats) {
    __shared__ float rs[4][128], rq[4][128];
    int t = threadIdx.x;
    int w = t >> 6, l = t & 63;
    int rg = t >> 5;      // 0..7 row-group
    int cq = t & 31;      // col-quad (4 cols)
    float s0 = 0, s1 = 0, s2 = 0, s3 = 0, q0 = 0, q1 = 0, q2 = 0, q3 = 0;
    for (int row = blockIdx.x * 8 + rg; row < NN; row += gridDim.x * 8) {
        float4 v = *(const float4*)&x[(size_t)row * INF + cq * 4];
        bf16x4 o; o[0] = (bf16)v.x; o[1] = (bf16)v.y; o[2] = (bf16)v.z; o[3] = (bf16)v.w;
        *(bf16x4*)&xb[(size_t)row * INF + cq * 4] = o;
        s0 += v.x; q0 += v.x * v.x;
        s1 += v.y; q1 += v.y * v.y;
        s2 += v.z; q2 += v.z * v.z;
        s3 += v.w; q3 += v.w * v.w;
    }
    // merge the two row-groups inside each wave (lanes l and l^32 share cq)
    s0 += __shfl_xor(s0, 32); s1 += __shfl_xor(s1, 32);
    s2 += __shfl_xor(s2, 32); s3 += __shfl_xor(s3, 32);
    q0 += __shfl_xor(q0, 32); q1 += __shfl_xor(q1, 32);
    q2 += __shfl_xor(q2, 32); q3 += __shfl_xor(q3, 32);
    if (l < 32) {
        rs[w][cq * 4 + 0] = s0; rs[w][cq * 4 + 1] = s1;
        rs[w][cq * 4 + 2] = s2; rs[w][cq * 4 + 3] = s3;
        rq[w][cq * 4 + 0] = q0; rq[w][cq * 4 + 1] = q1;
        rq[w][cq * 4 + 2] = q2; rq[w][cq * 4 + 3] = q3;
    }
    __syncthreads();
    if (t < 128) {
        atomicAdd(&stats[t],       rs[0][t] + rs[1][t] + rs[2][t] + rs[3][t]);
        atomicAdd(&stats[INF + t], rq[0][t] + rq[1][t] + rq[2][t] + rq[3][t]);
    }
}

// s = gamma * rsqrt(var+eps); t = beta - mean*s   (biased var)
__global__ void prep_st(const float* __restrict__ stats, int K,
                        const float* __restrict__ gamma, const float* __restrict__ beta,
                        float* __restrict__ s, float* __restrict__ t) {
    int j = blockIdx.x * blockDim.x + threadIdx.x;
    if (j < K) {
        const float invN = 1.0f / (float)NN;
        float mean = stats[j] * invN;
        float var  = stats[K + j] * invN - mean * mean;
        float sv   = gamma[j] * rsqrtf(var + 1e-5f);
        s[j] = sv;
        t[j] = beta[j] - mean * sv;
    }
}

// Wt[j][k] = bf16( (s?s[k]:1) * W[k][j] ) via LDS 64x64 tile transpose.
// grid (8, K/64); block 256. Coalesced reads AND writes.
__global__ __launch_bounds__(256)
void fold_wt(const float* __restrict__ s, const float* __restrict__ W,
             bf16* __restrict__ Wt, int K) {
    __shared__ float tile[64][68];
    __shared__ float sarr[64];
    int j0 = blockIdx.x * 64, k0 = blockIdx.y * 64;
    int t = threadIdx.x;
    if (t < 64) sarr[t] = s ? s[k0 + t] : 1.0f;
    int kk = t >> 2, jq = t & 3;
#pragma unroll
    for (int i = 0; i < 4; i++) {
        float4 v = *(const float4*)&W[(size_t)(k0 + kk) * DD + j0 + jq * 16 + i * 4];
        *(float4*)&tile[kk][jq * 16 + i * 4] = v;
    }
    __syncthreads();
    int jj = t >> 2, kq = t & 3;
    bf16 ov[16];
#pragma unroll
    for (int i = 0; i < 16; i++)
        ov[i] = (bf16)(tile[kq * 16 + i][jj] * sarr[kq * 16 + i]);
    bf16* dst = &Wt[(size_t)(j0 + jj) * K + k0 + kq * 16];
    *(u32x4*)dst       = *(u32x4*)&ov[0];
    *(u32x4*)(dst + 8) = *(u32x4*)&ov[8];
}

// bp[j] = b[j] + sum_k t[k]*W[k][j]; grid 8, block 256 (4 k-lanes x 64 j)
__global__ __launch_bounds__(256)
void fold_b(const float* __restrict__ tv, const float* __restrict__ W,
            const float* __restrict__ b, float* __restrict__ bp, int K) {
    __shared__ float red[4][64];
    int jj = threadIdx.x & 63, kr = threadIdx.x >> 6;
    int j = blockIdx.x * 64 + jj;
    float acc = 0.f;
    for (int k = kr; k < K; k += 4)
        acc += tv[k] * W[(size_t)k * DD + j];
    red[kr][jj] = acc;
    __syncthreads();
    if (kr == 0) bp[j] = b[j] + red[0][jj] + red[1][jj] + red[2][jj] + red[3][jj];
}

// ---------------------------------------------------------------------------
// MFMA GEMM: out row-block x col-block, A: M x K bf16, Wt: 512 x K bf16 (pre-T).
// grid (4, ceil(M/128)): col-block FASTEST -> the 4 blocks sharing an A-tile
// are temporally adjacent => A fetched ~once from HBM (L3/L2 serve the rest).
// block 256 = 4 waves; wave (wr,wc) owns 64x64 via 4x4 mfma_f32_16x16x32_bf16.
// LDS staging rows padded to 72 bf16; C/D layout col=lane&15,row=(lane>>4)*4+reg.
// MODE 0: plain store. MODE 1: + fused column sum/sumsq (atomics).
// MODE 2: stats + segment-pool into R, NO H store (layer3 feeds only pooling).
// MODE 0/1 store via LDS C-tile (stride 136) -> fully-coalesced 16B stores.
// ---------------------------------------------------------------------------
template <int K, int MODE>
__global__ __launch_bounds__(256, 2)
void gemm_mfma(const bf16* __restrict__ A, const bf16* __restrict__ Wt,
               const float* __restrict__ bias, bf16* __restrict__ H, int M,
               float* __restrict__ stats, const int* __restrict__ batch,
               float* __restrict__ R) {
    __shared__ bf16 smem[2 * 128 * 72];          // As | Bs ; reused as C-tile
    bf16* As = smem;
    bf16* Bs = smem + 128 * 72;
    const int t  = threadIdx.x;
    const int l  = t & 63;
    const int w  = t >> 6;
    const int wr = w >> 1, wc = w & 1;
    const int col0 = blockIdx.x * 128;           // x fastest = col block
    const int row0 = blockIdx.y * 128;
    const int sr = t >> 1;
    const int sh = t & 1;

    f32x4 acc[4][4];
#pragma unroll
    for (int m = 0; m < 4; m++)
#pragma unroll
        for (int n = 0; n < 4; n++) acc[m][n] = (f32x4){0.f, 0.f, 0.f, 0.f};

    int ar = row0 + sr; if (ar >= M) ar = M - 1;
    const bf16* Asrc = A  + (size_t)ar * K + sh * 32;
    const bf16* Bsrc = Wt + (size_t)(col0 + sr) * K + sh * 32;

#pragma unroll 1
    for (int k0 = 0; k0 < K; k0 += 64) {
#pragma unroll
        for (int c = 0; c < 4; c++) {
            *(u32x4*)&As[sr * 72 + sh * 32 + c * 8] = *(const u32x4*)(Asrc + k0 + c * 8);
            *(u32x4*)&Bs[sr * 72 + sh * 32 + c * 8] = *(const u32x4*)(Bsrc + k0 + c * 8);
        }
        __syncthreads();
#pragma unroll
        for (int ks = 0; ks < 2; ks++) {
            bf16x8 af[4], bfr[4];
#pragma unroll
            for (int m = 0; m < 4; m++)
                af[m] = *(const bf16x8*)&As[(wr * 64 + m * 16 + (l & 15)) * 72 + ks * 32 + (l >> 4) * 8];
#pragma unroll
            for (int n = 0; n < 4; n++)
                bfr[n] = *(const bf16x8*)&Bs[(wc * 64 + n * 16 + (l & 15)) * 72 + ks * 32 + (l >> 4) * 8];
#pragma unroll
            for (int m = 0; m < 4; m++)
#pragma unroll
                for (int n = 0; n < 4; n++)
                    acc[m][n] = __builtin_amdgcn_mfma_f32_16x16x32_bf16(af[m], bfr[n], acc[m][n], 0, 0, 0);
        }
        __syncthreads();
    }

    float csumA[4], csqA[4];

    if (MODE <= 1) {
        // bias+relu -> C-tile in LDS (stride 136 bf16 = 272B), stats in regs
        bf16* ct = smem;
#pragma unroll
        for (int n = 0; n < 4; n++) {
            int lc = wc * 64 + n * 16 + (l & 15);
            float bv = bias[col0 + lc];
            float cs = 0.f, cq = 0.f;
#pragma unroll
            for (int m = 0; m < 4; m++) {
#pragma unroll
                for (int q = 0; q < 4; q++) {
                    int lr = wr * 64 + m * 16 + (l >> 4) * 4 + q;
                    float v = acc[m][n][q] + bv;
                    v = v > 0.f ? v : 0.f;
                    ct[lr * 136 + lc] = (bf16)v;
                    if (MODE == 1 && row0 + lr < M) { cs += v; cq += v * v; }
                }
            }
            csumA[n] = cs; csqA[n] = cq;
        }
        __syncthreads();
        // coalesced store: 8 iters x 256 threads x 16B = 32KB tile, 1KB/wave-instr
        {
            const char* cts = (const char*)ct;
            char* Hc = (char*)H;
#pragma unroll
            for (int i = 0; i < 8; i++) {
                int fo = i * 4096 + t * 16;
                int r  = fo >> 8;          // tile row (256B per row)
                int cb = fo & 255;         // byte within row
                if (row0 + r < M)
                    *(u32x4*)(Hc + ((size_t)(row0 + r) * (DD * 2) + (size_t)col0 * 2 + cb)) =
                        *(const u32x4*)(cts + r * 272 + cb);
            }
        }
    } else {
        // MODE 2: stats + segment-pool straight from registers; no H store.
        int gid[4][4];
#pragma unroll
        for (int m = 0; m < 4; m++)
#pragma unroll
            for (int q = 0; q < 4; q++) {
                int grow = row0 + wr * 64 + m * 16 + (l >> 4) * 4 + q;
                gid[m][q] = (grow < M) ? batch[grow] : -1;
            }
#pragma unroll
        for (int n = 0; n < 4; n++) {
            int col = col0 + wc * 64 + n * 16 + (l & 15);
            float bv = bias[col];
            float cs = 0.f, cq = 0.f;
            float ps = 0.f; int gc = -1;
#pragma unroll
            for (int m = 0; m < 4; m++) {
#pragma unroll
                for (int q = 0; q < 4; q++) {
                    int g = gid[m][q];
                    if (g >= 0) {
                        float v = acc[m][n][q] + bv;
                        v = v > 0.f ? v : 0.f;
                        cs += v; cq += v * v;
                        if (g != gc) {
                            if (gc >= 0) atomicAdd(&R[(size_t)gc * DD + col], ps);
                            ps = 0.f; gc = g;
                        }
                        ps += v;
                    }
                }
            }
            if (gc >= 0) atomicAdd(&R[(size_t)gc * DD + col], ps);
            csumA[n] = cs; csqA[n] = cq;
        }
    }

    if (MODE >= 1) {
        // wave-internal column reduce (lanes l, l^16, l^32, l^48 share a col)
#pragma unroll
        for (int n = 0; n < 4; n++) {
            float cs = csumA[n], cq = csqA[n];
            cs += __shfl_xor(cs, 16); cs += __shfl_xor(cs, 32);
            cq += __shfl_xor(cq, 16); cq += __shfl_xor(cq, 32);
            if ((l >> 4) == 0) {
                int col = col0 + wc * 64 + n * 16 + l;
                atomicAdd(&stats[col], cs);
                atomicAdd(&stats[DD + col], cq);
            }
        }
    }
}

// P[g][j] = R[g][j]*s4[j] + cnt_g*t4[j]
__global__ __launch_bounds__(512)
void pool_fin(const float* __restrict__ R, const int* __restrict__ starts,
              const float* __restrict__ s4, const float* __restrict__ t4,
              float* __restrict__ P) {
    int g = blockIdx.x, j = threadIdx.x;
    float cnt = (float)(starts[g + 1] - starts[g]);
    P[g * DD + j] = R[(size_t)g * DD + j] * s4[j] + cnt * t4[j];
}

// ---------------------------------------------------------------------------
// head: per-graph  prelu(P@fc1+b) -> sigmoid(@fc2+b) -> @fc3+b  (fp32)
// ---------------------------------------------------------------------------
__global__ __launch_bounds__(256)
void head_k(const float* __restrict__ P,
            const float* __restrict__ fc1_w, const float* __restrict__ fc1_b,
            const float* __restrict__ fc2_w, const float* __restrict__ fc2_b,
            const float* __restrict__ fc3_w, const float* __restrict__ fc3_b,
            const float* __restrict__ a3, float* __restrict__ out) {
    __shared__ float p[DD], y1[DD], y2[DD / 2];
    int g = blockIdx.x, t = threadIdx.x;
    p[t]       = P[g * DD + t];
    p[t + 256] = P[g * DD + t + 256];
    __syncthreads();
    float alpha = a3[0];

    float acc0 = fc1_b[t], acc1 = fc1_b[t + 256];
    for (int k = 0; k < DD; k++) {
        float pv = p[k];
        acc0 = fmaf(pv, fc1_w[(size_t)k * DD + t], acc0);
        acc1 = fmaf(pv, fc1_w[(size_t)k * DD + t + 256], acc1);
    }
    y1[t]       = acc0 >= 0.f ? acc0 : alpha * acc0;
    y1[t + 256] = acc1 >= 0.f ? acc1 : alpha * acc1;
    __syncthreads();

    float acc = fc2_b[t];
    for (int k = 0; k < DD; k++) acc = fmaf(y1[k], fc2_w[(size_t)k * (DD / 2) + t], acc);
    y2[t] = 1.0f / (1.0f + expf(-acc));
    __syncthreads();

    if (t < CC) {
        float a = fc3_b[t];
        for (int k = 0; k < DD / 2; k++) a = fmaf(y2[k], fc3_w[(size_t)k * CC + t], a);
        out[g * CC + t] = a;
    }
}

// ---------------------------------------------------------------------------
// launch
// ---------------------------------------------------------------------------
extern "C" void kernel_launch(void* const* d_in, const int* in_sizes, int n_in,
                              void* d_out, int out_size, void* d_ws, size_t ws_size,
                              hipStream_t stream) {
    const float* x     = (const float*)d_in[0];
    /* d_in[1] edge_index: unused (ChebConv K=1 == linear) */
    const int*   batch = (const int*)d_in[2];
    const float* bn1_g = (const float*)d_in[3];
    const float* bn1_b = (const float*)d_in[4];
    const float* w0    = (const float*)d_in[5];
    const float* b0    = (const float*)d_in[6];
    const float* w1    = (const float*)d_in[7];
    const float* bb1   = (const float*)d_in[8];
    const float* w2    = (const float*)d_in[9];
    const float* bb2   = (const float*)d_in[10];
    const float* w3    = (const float*)d_in[11];
    const float* bb3   = (const float*)d_in[12];
    const float* bn3_g = (const float*)d_in[13];
    const float* bn3_b = (const float*)d_in[14];
    const float* a3    = (const float*)d_in[15];
    const float* fc1_w = (const float*)d_in[16];
    const float* fc1_b = (const float*)d_in[17];
    const float* fc2_w = (const float*)d_in[18];
    const float* fc2_b = (const float*)d_in[19];
    const float* fc3_w = (const float*)d_in[20];
    const float* fc3_b = (const float*)d_in[21];
    float* out = (float*)d_out;

    // ---- workspace layout ----
    char* base = (char*)d_ws;
    const size_t HBYTES = (size_t)NN * DD * 2;       // 102,400,000
    bf16* Ha = (bf16*)base;
    bf16* Hb = (bf16*)(base + HBYTES);
    bf16* Xb = Hb;                                   // alias: dead after layer0
    bf16* Wt = (bf16*)(base + 2 * HBYTES);           // 512*512*2 = 524,288
    float* f = (float*)(base + 2 * HBYTES + 524288);
    size_t off = 0;
    float* stats  = f + off; off += 3328;            // x(256) + 3 layers (1024 each)
    float* R      = f + off; off += (size_t)GG * DD; // 32,768 (zeroed with stats)
    float* statsX = stats;
    float* stats2 = stats + 256;
    float* stats3 = stats + 1280;
    float* stats4 = stats + 2304;
    float* s1 = f + off; off += 128;
    float* t1 = f + off; off += 128;
    float* s2 = f + off; off += 512;
    float* t2 = f + off; off += 512;
    float* s3 = f + off; off += 512;
    float* t3 = f + off; off += 512;
    float* s4 = f + off; off += 512;
    float* t4 = f + off; off += 512;
    float* b0p = f + off; off += 512;
    float* bp  = f + off; off += 512;
    float* P   = f + off; off += (size_t)GG * DD;    // 32,768
    int*   starts = (int*)(f + off); off += 128;

    (void)in_sizes; (void)n_in; (void)out_size; (void)ws_size;

    const dim3 ggrid(4, (NN + 127) / 128);           // col-block fastest
    const int kZeroCount = 3328 + GG * DD;           // stats + R contiguous

    zero_k<<<(kZeroCount + 255) / 256, 256, 0, stream>>>(stats, kZeroCount);
    bounds_k<<<1, 128, 0, stream>>>(batch, starts);

    // BN1 (exact fp32 stats on x) fused with bf16 cast; fold into layer0
    colstats_cvt<<<256, 256, 0, stream>>>(x, Xb, statsX);
    prep_st<<<1, 128, 0, stream>>>(statsX, 128, bn1_g, bn1_b, s1, t1);
    fold_wt<<<dim3(8, INF / 64), 256, 0, stream>>>(s1, w0, Wt, INF);
    fold_b<<<8, 256, 0, stream>>>(t1, w0, b0, b0p, INF);
    // layer0: Ha = relu(Xb @ W0' + b0')
    gemm_mfma<INF, 0><<<ggrid, 256, 0, stream>>>(Xb, Wt, b0p, Ha, NN, nullptr, nullptr, nullptr);

    // layer1: Hb = relu(Ha @ w1 + bb1) + fused stats2
    fold_wt<<<dim3(8, DD / 64), 256, 0, stream>>>(nullptr, w1, Wt, DD);
    gemm_mfma<DD, 1><<<ggrid, 256, 0, stream>>>(Ha, Wt, bb1, Hb, NN, stats2, nullptr, nullptr);

    // layer2: fold BN(stats2) into w2; Ha = relu(Hb @ W2' + b2') + stats3
    prep_st<<<2, 256, 0, stream>>>(stats2, 512, bn3_g, bn3_b, s2, t2);
    fold_wt<<<dim3(8, DD / 64), 256, 0, stream>>>(s2, w2, Wt, DD);
    fold_b<<<8, 256, 0, stream>>>(t2, w2, bb2, bp, DD);
    gemm_mfma<DD, 1><<<ggrid, 256, 0, stream>>>(Hb, Wt, bp, Ha, NN, stats3, nullptr, nullptr);

    // layer3: fold BN(stats3) into w3; stats4 + segment-pool fused, no H store
    prep_st<<<2, 256, 0, stream>>>(stats3, 512, bn3_g, bn3_b, s3, t3);
    fold_wt<<<dim3(8, DD / 64), 256, 0, stream>>>(s3, w3, Wt, DD);
    fold_b<<<8, 256, 0, stream>>>(t3, w3, bb3, bp, DD);
    gemm_mfma<DD, 2><<<ggrid, 256, 0, stream>>>(Ha, Wt, bp, nullptr, NN, stats4, batch, R);

    // final BN folded into pooled sums
    prep_st<<<2, 256, 0, stream>>>(stats4, 512, bn3_g, bn3_b, s4, t4);
    pool_fin<<<GG, 512, 0, stream>>>(R, starts, s4, t4, P);
    head_k<<<GG, 256, 0, stream>>>(P, fc1_w, fc1_b, fc2_w, fc2_b, fc3_w, fc3_b, a3, out);
}

// Round 10
// 605.477 us; speedup vs baseline: 6.6011x; 1.0556x over previous
//
#include <hip/hip_runtime.h>
#include <math.h>

#define NN 100000   // nodes
#define INF 128     // input features
#define DD  512     // hidden dim
#define GG  64      // graphs
#define CC  10      // classes

typedef __bf16 bf16;
typedef __bf16 bf16x8 __attribute__((ext_vector_type(8)));
typedef __bf16 bf16x4 __attribute__((ext_vector_type(4)));
typedef float  f32x4  __attribute__((ext_vector_type(4)));
typedef unsigned int u32x4 __attribute__((ext_vector_type(4)));

// async global->LDS, 16 bytes per lane. LDS dest is wave-uniform base +
// lane*16 (HW-defined); global src is per-lane.
__device__ __forceinline__ void gld16(const bf16* g, bf16* l) {
    __builtin_amdgcn_global_load_lds(
        (const __attribute__((address_space(1))) unsigned int*)g,
        (__attribute__((address_space(3))) unsigned int*)l, 16, 0, 0);
}

// ---------------------------------------------------------------------------
// small utility kernels
// ---------------------------------------------------------------------------

__global__ void zero_k(float* __restrict__ p, int n) {
    int i = blockIdx.x * blockDim.x + threadIdx.x;
    if (i < n) p[i] = 0.0f;
}

__global__ void bounds_k(const int* __restrict__ batch, int* __restrict__ starts) {
    int g = threadIdx.x;
    if (g <= GG) {
        int lo = 0, hi = NN;
        while (lo < hi) {
            int mid = (lo + hi) >> 1;
            if (batch[mid] < g) lo = mid + 1; else hi = mid;
        }
        starts[g] = lo;
    }
}

// fused: exact fp32 column stats of x (NN x 128) + bf16 cast, vectorized.
__global__ __launch_bounds__(256)
void colstats_cvt(const float* __restrict__ x, bf16* __restrict__ xb,
                  float* __restrict__ stats) {
    __shared__ float rs[4][128], rq[4][128];
    int t = threadIdx.x;
    int w = t >> 6, l = t & 63;
    int rg = t >> 5;      // 0..7 row-group
    int cq = t & 31;      // col-quad (4 cols)
    float s0 = 0, s1 = 0, s2 = 0, s3 = 0, q0 = 0, q1 = 0, q2 = 0, q3 = 0;
    for (int row = blockIdx.x * 8 + rg; row < NN; row += gridDim.x * 8) {
        float4 v = *(const float4*)&x[(size_t)row * INF + cq * 4];
        bf16x4 o; o[0] = (bf16)v.x; o[1] = (bf16)v.y; o[2] = (bf16)v.z; o[3] = (bf16)v.w;
        *(bf16x4*)&xb[(size_t)row * INF + cq * 4] = o;
        s0 += v.x; q0 += v.x * v.x;
        s1 += v.y; q1 += v.y * v.y;
        s2 += v.z; q2 += v.z * v.z;
        s3 += v.w; q3 += v.w * v.w;
    }
    s0 += __shfl_xor(s0, 32); s1 += __shfl_xor(s1, 32);
    s2 += __shfl_xor(s2, 32); s3 += __shfl_xor(s3, 32);
    q0 += __shfl_xor(q0, 32); q1 += __shfl_xor(q1, 32);
    q2 += __shfl_xor(q2, 32); q3 += __shfl_xor(q3, 32);
    if (l < 32) {
        rs[w][cq * 4 + 0] = s0; rs[w][cq * 4 + 1] = s1;
        rs[w][cq * 4 + 2] = s2; rs[w][cq * 4 + 3] = s3;
        rq[w][cq * 4 + 0] = q0; rq[w][cq * 4 + 1] = q1;
        rq[w][cq * 4 + 2] = q2; rq[w][cq * 4 + 3] = q3;
    }
    __syncthreads();
    if (t < 128) {
        atomicAdd(&stats[t],       rs[0][t] + rs[1][t] + rs[2][t] + rs[3][t]);
        atomicAdd(&stats[INF + t], rq[0][t] + rq[1][t] + rq[2][t] + rq[3][t]);
    }
}

// s = gamma * rsqrt(var+eps); t = beta - mean*s   (biased var)
__global__ void prep_st(const float* __restrict__ stats, int K,
                        const float* __restrict__ gamma, const float* __restrict__ beta,
                        float* __restrict__ s, float* __restrict__ t) {
    int j = blockIdx.x * blockDim.x + threadIdx.x;
    if (j < K) {
        const float invN = 1.0f / (float)NN;
        float mean = stats[j] * invN;
        float var  = stats[K + j] * invN - mean * mean;
        float sv   = gamma[j] * rsqrtf(var + 1e-5f);
        s[j] = sv;
        t[j] = beta[j] - mean * sv;
    }
}

// Wt[j][k] = bf16( (s?s[k]:1) * W[k][j] ) via LDS 64x64 tile transpose.
__global__ __launch_bounds__(256)
void fold_wt(const float* __restrict__ s, const float* __restrict__ W,
             bf16* __restrict__ Wt, int K) {
    __shared__ float tile[64][68];
    __shared__ float sarr[64];
    int j0 = blockIdx.x * 64, k0 = blockIdx.y * 64;
    int t = threadIdx.x;
    if (t < 64) sarr[t] = s ? s[k0 + t] : 1.0f;
    int kk = t >> 2, jq = t & 3;
#pragma unroll
    for (int i = 0; i < 4; i++) {
        float4 v = *(const float4*)&W[(size_t)(k0 + kk) * DD + j0 + jq * 16 + i * 4];
        *(float4*)&tile[kk][jq * 16 + i * 4] = v;
    }
    __syncthreads();
    int jj = t >> 2, kq = t & 3;
    bf16 ov[16];
#pragma unroll
    for (int i = 0; i < 16; i++)
        ov[i] = (bf16)(tile[kq * 16 + i][jj] * sarr[kq * 16 + i]);
    bf16* dst = &Wt[(size_t)(j0 + jj) * K + k0 + kq * 16];
    *(u32x4*)dst       = *(u32x4*)&ov[0];
    *(u32x4*)(dst + 8) = *(u32x4*)&ov[8];
}

// bp[j] = b[j] + sum_k t[k]*W[k][j]; grid 8, block 256 (4 k-lanes x 64 j)
__global__ __launch_bounds__(256)
void fold_b(const float* __restrict__ tv, const float* __restrict__ W,
            const float* __restrict__ b, float* __restrict__ bp, int K) {
    __shared__ float red[4][64];
    int jj = threadIdx.x & 63, kr = threadIdx.x >> 6;
    int j = blockIdx.x * 64 + jj;
    float acc = 0.f;
    for (int k = kr; k < K; k += 4)
        acc += tv[k] * W[(size_t)k * DD + j];
    red[kr][jj] = acc;
    __syncthreads();
    if (kr == 0) bp[j] = b[j] + red[0][jj] + red[1][jj] + red[2][jj] + red[3][jj];
}

// ---------------------------------------------------------------------------
// MFMA GEMM, global_load_lds staging + st-style XOR swizzle.
// A: M x K bf16, Wt: 512 x K bf16 (pre-T). grid (4, ceil(M/128)).
// LDS tiles LINEAR [128 rows][64 k] bf16 (128B/row, required by gload_lds);
// bank conflicts avoided by slot permutation: LDS (row, slot) holds global
// (row, slot ^ (row&7)) [16B slots]; ds_read applies the same XOR. Lanes
// 0..15 of a fragment read hit 8 distinct slots -> 2-way alias (free).
// MODE 0: plain store. MODE 1: + fused column sum/sumsq.
// MODE 2: stats + segment-pool into R, NO H store (layer3 feeds only pooling).
// MODE 0/1 store via LDS C-tile (stride 136) -> fully-coalesced 16B stores.
// ---------------------------------------------------------------------------
template <int K, int MODE>
__global__ __launch_bounds__(256, 4)
void gemm_mfma(const bf16* __restrict__ A, const bf16* __restrict__ Wt,
               const float* __restrict__ bias, bf16* __restrict__ H, int M,
               float* __restrict__ stats, const int* __restrict__ batch,
               float* __restrict__ R) {
    __shared__ bf16 smem[18432];                 // 36,864 B: As(16K)|Bs(16K); C-tile reuse
    bf16* As = smem;                             // [128][64] linear
    bf16* Bs = smem + 8192;
    const int t  = threadIdx.x;
    const int l  = t & 63;
    const int w  = t >> 6;
    const int wr = w >> 1, wc = w & 1;
    const int col0 = blockIdx.x * 128;           // x fastest = col block
    const int row0 = blockIdx.y * 128;

    // staging geometry: thread covers rows c*32 + w*8 + (l>>3), slot l&7
    const int srow = w * 8 + (l >> 3);
    const int sslt = l & 7;

    f32x4 acc[4][4];
#pragma unroll
    for (int m = 0; m < 4; m++)
#pragma unroll
        for (int n = 0; n < 4; n++) acc[m][n] = (f32x4){0.f, 0.f, 0.f, 0.f};

#pragma unroll 1
    for (int k0 = 0; k0 < K; k0 += 64) {
#pragma unroll
        for (int c = 0; c < 4; c++) {
            int r  = c * 32 + srow;              // LDS row 0..127
            int sg = sslt ^ (r & 7);             // pre-swizzled source slot
            int ga = row0 + r; if (ga >= M) ga = M - 1;
            gld16(A  + (size_t)ga * K + k0 + sg * 8,
                  (bf16*)((char*)As + c * 4096 + w * 1024));
            gld16(Wt + (size_t)(col0 + r) * K + k0 + sg * 8,
                  (bf16*)((char*)Bs + c * 4096 + w * 1024));
        }
        __syncthreads();                         // drains vmcnt before barrier
#pragma unroll
        for (int ks = 0; ks < 2; ks++) {
            bf16x8 af[4], bfr[4];
#pragma unroll
            for (int m = 0; m < 4; m++) {
                int r = wr * 64 + m * 16 + (l & 15);
                af[m] = *(const bf16x8*)((const char*)As + r * 128 +
                        ((((ks << 2) + (l >> 4)) ^ (r & 7)) << 4));
            }
#pragma unroll
            for (int n = 0; n < 4; n++) {
                int r = wc * 64 + n * 16 + (l & 15);
                bfr[n] = *(const bf16x8*)((const char*)Bs + r * 128 +
                         ((((ks << 2) + (l >> 4)) ^ (r & 7)) << 4));
            }
#pragma unroll
            for (int m = 0; m < 4; m++)
#pragma unroll
                for (int n = 0; n < 4; n++)
                    acc[m][n] = __builtin_amdgcn_mfma_f32_16x16x32_bf16(af[m], bfr[n], acc[m][n], 0, 0, 0);
        }
        __syncthreads();
    }

    float csumA[4], csqA[4];

    if (MODE <= 1) {
        // bias+relu -> C-tile in LDS (stride 136 bf16 = 272B), stats in regs
        bf16* ct = smem;
#pragma unroll
        for (int n = 0; n < 4; n++) {
            int lc = wc * 64 + n * 16 + (l & 15);
            float bv = bias[col0 + lc];
            float cs = 0.f, cq = 0.f;
#pragma unroll
            for (int m = 0; m < 4; m++) {
#pragma unroll
                for (int q = 0; q < 4; q++) {
                    int lr = wr * 64 + m * 16 + (l >> 4) * 4 + q;
                    float v = acc[m][n][q] + bv;
                    v = v > 0.f ? v : 0.f;
                    ct[lr * 136 + lc] = (bf16)v;
                    if (MODE == 1 && row0 + lr < M) { cs += v; cq += v * v; }
                }
            }
            csumA[n] = cs; csqA[n] = cq;
        }
        __syncthreads();
        // coalesced store: 8 iters x 256 threads x 16B = 32KB tile
        {
            const char* cts = (const char*)ct;
            char* Hc = (char*)H;
#pragma unroll
            for (int i = 0; i < 8; i++) {
                int fo = i * 4096 + t * 16;
                int r  = fo >> 8;          // tile row (256B of payload per row)
                int cb = fo & 255;
                if (row0 + r < M)
                    *(u32x4*)(Hc + ((size_t)(row0 + r) * (DD * 2) + (size_t)col0 * 2 + cb)) =
                        *(const u32x4*)(cts + r * 272 + cb);
            }
        }
    } else {
        // MODE 2: stats + segment-pool straight from registers; no H store.
        int gid[4][4];
#pragma unroll
        for (int m = 0; m < 4; m++)
#pragma unroll
            for (int q = 0; q < 4; q++) {
                int grow = row0 + wr * 64 + m * 16 + (l >> 4) * 4 + q;
                gid[m][q] = (grow < M) ? batch[grow] : -1;
            }
#pragma unroll
        for (int n = 0; n < 4; n++) {
            int col = col0 + wc * 64 + n * 16 + (l & 15);
            float bv = bias[col];
            float cs = 0.f, cq = 0.f;
            float ps = 0.f; int gc = -1;
#pragma unroll
            for (int m = 0; m < 4; m++) {
#pragma unroll
                for (int q = 0; q < 4; q++) {
                    int g = gid[m][q];
                    if (g >= 0) {
                        float v = acc[m][n][q] + bv;
                        v = v > 0.f ? v : 0.f;
                        cs += v; cq += v * v;
                        if (g != gc) {
                            if (gc >= 0) atomicAdd(&R[(size_t)gc * DD + col], ps);
                            ps = 0.f; gc = g;
                        }
                        ps += v;
                    }
                }
            }
            if (gc >= 0) atomicAdd(&R[(size_t)gc * DD + col], ps);
            csumA[n] = cs; csqA[n] = cq;
        }
    }

    if (MODE >= 1) {
#pragma unroll
        for (int n = 0; n < 4; n++) {
            float cs = csumA[n], cq = csqA[n];
            cs += __shfl_xor(cs, 16); cs += __shfl_xor(cs, 32);
            cq += __shfl_xor(cq, 16); cq += __shfl_xor(cq, 32);
            if ((l >> 4) == 0) {
                int col = col0 + wc * 64 + n * 16 + l;
                atomicAdd(&stats[col], cs);
                atomicAdd(&stats[DD + col], cq);
            }
        }
    }
}

// P[g][j] = R[g][j]*s4[j] + cnt_g*t4[j]
__global__ __launch_bounds__(512)
void pool_fin(const float* __restrict__ R, const int* __restrict__ starts,
              const float* __restrict__ s4, const float* __restrict__ t4,
              float* __restrict__ P) {
    int g = blockIdx.x, j = threadIdx.x;
    float cnt = (float)(starts[g + 1] - starts[g]);
    P[g * DD + j] = R[(size_t)g * DD + j] * s4[j] + cnt * t4[j];
}

// ---------------------------------------------------------------------------
// head: per-graph  prelu(P@fc1+b) -> sigmoid(@fc2+b) -> @fc3+b  (fp32)
// ---------------------------------------------------------------------------
__global__ __launch_bounds__(256)
void head_k(const float* __restrict__ P,
            const float* __restrict__ fc1_w, const float* __restrict__ fc1_b,
            const float* __restrict__ fc2_w, const float* __restrict__ fc2_b,
            const float* __restrict__ fc3_w, const float* __restrict__ fc3_b,
            const float* __restrict__ a3, float* __restrict__ out) {
    __shared__ float p[DD], y1[DD], y2[DD / 2];
    int g = blockIdx.x, t = threadIdx.x;
    p[t]       = P[g * DD + t];
    p[t + 256] = P[g * DD + t + 256];
    __syncthreads();
    float alpha = a3[0];

    float acc0 = fc1_b[t], acc1 = fc1_b[t + 256];
    for (int k = 0; k < DD; k++) {
        float pv = p[k];
        acc0 = fmaf(pv, fc1_w[(size_t)k * DD + t], acc0);
        acc1 = fmaf(pv, fc1_w[(size_t)k * DD + t + 256], acc1);
    }
    y1[t]       = acc0 >= 0.f ? acc0 : alpha * acc0;
    y1[t + 256] = acc1 >= 0.f ? acc1 : alpha * acc1;
    __syncthreads();

    float acc = fc2_b[t];
    for (int k = 0; k < DD; k++) acc = fmaf(y1[k], fc2_w[(size_t)k * (DD / 2) + t], acc);
    y2[t] = 1.0f / (1.0f + expf(-acc));
    __syncthreads();

    if (t < CC) {
        float a = fc3_b[t];
        for (int k = 0; k < DD / 2; k++) a = fmaf(y2[k], fc3_w[(size_t)k * CC + t], a);
        out[g * CC + t] = a;
    }
}

// ---------------------------------------------------------------------------
// launch
// ---------------------------------------------------------------------------
extern "C" void kernel_launch(void* const* d_in, const int* in_sizes, int n_in,
                              void* d_out, int out_size, void* d_ws, size_t ws_size,
                              hipStream_t stream) {
    const float* x     = (const float*)d_in[0];
    /* d_in[1] edge_index: unused (ChebConv K=1 == linear) */
    const int*   batch = (const int*)d_in[2];
    const float* bn1_g = (const float*)d_in[3];
    const float* bn1_b = (const float*)d_in[4];
    const float* w0    = (const float*)d_in[5];
    const float* b0    = (const float*)d_in[6];
    const float* w1    = (const float*)d_in[7];
    const float* bb1   = (const float*)d_in[8];
    const float* w2    = (const float*)d_in[9];
    const float* bb2   = (const float*)d_in[10];
    const float* w3    = (const float*)d_in[11];
    const float* bb3   = (const float*)d_in[12];
    const float* bn3_g = (const float*)d_in[13];
    const float* bn3_b = (const float*)d_in[14];
    const float* a3    = (const float*)d_in[15];
    const float* fc1_w = (const float*)d_in[16];
    const float* fc1_b = (const float*)d_in[17];
    const float* fc2_w = (const float*)d_in[18];
    const float* fc2_b = (const float*)d_in[19];
    const float* fc3_w = (const float*)d_in[20];
    const float* fc3_b = (const float*)d_in[21];
    float* out = (float*)d_out;

    // ---- workspace layout ----
    char* base = (char*)d_ws;
    const size_t HBYTES = (size_t)NN * DD * 2;       // 102,400,000
    bf16* Ha = (bf16*)base;
    bf16* Hb = (bf16*)(base + HBYTES);
    bf16* Xb = Hb;                                   // alias: dead after layer0
    bf16* Wt = (bf16*)(base + 2 * HBYTES);           // 512*512*2 = 524,288
    float* f = (float*)(base + 2 * HBYTES + 524288);
    size_t off = 0;
    float* stats  = f + off; off += 3328;            // x(256) + 3 layers (1024 each)
    float* R      = f + off; off += (size_t)GG * DD; // 32,768 (zeroed with stats)
    float* statsX = stats;
    float* stats2 = stats + 256;
    float* stats3 = stats + 1280;
    float* stats4 = stats + 2304;
    float* s1 = f + off; off += 128;
    float* t1 = f + off; off += 128;
    float* s2 = f + off; off += 512;
    float* t2 = f + off; off += 512;
    float* s3 = f + off; off += 512;
    float* t3 = f + off; off += 512;
    float* s4 = f + off; off += 512;
    float* t4 = f + off; off += 512;
    float* b0p = f + off; off += 512;
    float* bp  = f + off; off += 512;
    float* P   = f + off; off += (size_t)GG * DD;    // 32,768
    int*   starts = (int*)(f + off); off += 128;

    (void)in_sizes; (void)n_in; (void)out_size; (void)ws_size;

    const dim3 ggrid(4, (NN + 127) / 128);           // col-block fastest
    const int kZeroCount = 3328 + GG * DD;           // stats + R contiguous

    zero_k<<<(kZeroCount + 255) / 256, 256, 0, stream>>>(stats, kZeroCount);
    bounds_k<<<1, 128, 0, stream>>>(batch, starts);

    // BN1 (exact fp32 stats on x) fused with bf16 cast; fold into layer0
    colstats_cvt<<<256, 256, 0, stream>>>(x, Xb, statsX);
    prep_st<<<1, 128, 0, stream>>>(statsX, 128, bn1_g, bn1_b, s1, t1);
    fold_wt<<<dim3(8, INF / 64), 256, 0, stream>>>(s1, w0, Wt, INF);
    fold_b<<<8, 256, 0, stream>>>(t1, w0, b0, b0p, INF);
    // layer0: Ha = relu(Xb @ W0' + b0')
    gemm_mfma<INF, 0><<<ggrid, 256, 0, stream>>>(Xb, Wt, b0p, Ha, NN, nullptr, nullptr, nullptr);

    // layer1: Hb = relu(Ha @ w1 + bb1) + fused stats2
    fold_wt<<<dim3(8, DD / 64), 256, 0, stream>>>(nullptr, w1, Wt, DD);
    gemm_mfma<DD, 1><<<ggrid, 256, 0, stream>>>(Ha, Wt, bb1, Hb, NN, stats2, nullptr, nullptr);

    // layer2: fold BN(stats2) into w2; Ha = relu(Hb @ W2' + b2') + stats3
    prep_st<<<2, 256, 0, stream>>>(stats2, 512, bn3_g, bn3_b, s2, t2);
    fold_wt<<<dim3(8, DD / 64), 256, 0, stream>>>(s2, w2, Wt, DD);
    fold_b<<<8, 256, 0, stream>>>(t2, w2, bb2, bp, DD);
    gemm_mfma<DD, 1><<<ggrid, 256, 0, stream>>>(Hb, Wt, bp, Ha, NN, stats3, nullptr, nullptr);

    // layer3: fold BN(stats3) into w3; stats4 + segment-pool fused, no H store
    prep_st<<<2, 256, 0, stream>>>(stats3, 512, bn3_g, bn3_b, s3, t3);
    fold_wt<<<dim3(8, DD / 64), 256, 0, stream>>>(s3, w3, Wt, DD);
    fold_b<<<8, 256, 0, stream>>>(t3, w3, bb3, bp, DD);
    gemm_mfma<DD, 2><<<ggrid, 256, 0, stream>>>(Ha, Wt, bp, nullptr, NN, stats4, batch, R);

    // final BN folded into pooled sums
    prep_st<<<2, 256, 0, stream>>>(stats4, 512, bn3_g, bn3_b, s4, t4);
    pool_fin<<<GG, 512, 0, stream>>>(R, starts, s4, t4, P);
    head_k<<<GG, 256, 0, stream>>>(P, fc1_w, fc1_b, fc2_w, fc2_b, fc3_w, fc3_b, a3, out);
}

// Round 11
// 603.591 us; speedup vs baseline: 6.6218x; 1.0031x over previous
//
#include <hip/hip_runtime.h>
#include <math.h>

#define NN 100000   // nodes
#define INF 128     // input features
#define DD  512     // hidden dim
#define GG  64      // graphs
#define CC  10      // classes

typedef __bf16 bf16;
typedef __bf16 bf16x8 __attribute__((ext_vector_type(8)));
typedef __bf16 bf16x4 __attribute__((ext_vector_type(4)));
typedef float  f32x4  __attribute__((ext_vector_type(4)));
typedef unsigned int u32x4 __attribute__((ext_vector_type(4)));

#define NRB ((NN + 127) / 128)          // 782 row-blocks
#define CPX ((NRB + 7) / 8)             // 98 row-blocks per XCD chunk
#define GEMM_GRID (8 * CPX * 4)         // 3136 (padded; tail blocks exit)

// async global->LDS, 16 bytes per lane. LDS dest is wave-uniform base +
// lane*16 (HW-defined); global src is per-lane.
__device__ __forceinline__ void gld16(const bf16* g, bf16* l) {
    __builtin_amdgcn_global_load_lds(
        (const __attribute__((address_space(1))) unsigned int*)g,
        (__attribute__((address_space(3))) unsigned int*)l, 16, 0, 0);
}

// BN fold helpers: s = gamma*rsqrt(var+eps), t = beta - mean*s (biased var)
__device__ __forceinline__ float bn_s(const float* stats, const float* gamma,
                                      int K, int k) {
    const float invN = 1.0f / (float)NN;
    float mean = stats[k] * invN;
    float var  = stats[K + k] * invN - mean * mean;
    return gamma[k] * rsqrtf(var + 1e-5f);
}
__device__ __forceinline__ float bn_t(const float* stats, const float* gamma,
                                      const float* beta, int K, int k) {
    const float invN = 1.0f / (float)NN;
    float mean = stats[k] * invN;
    float var  = stats[K + k] * invN - mean * mean;
    float sv   = gamma[k] * rsqrtf(var + 1e-5f);
    return beta[k] - mean * sv;
}

// ---------------------------------------------------------------------------
// small utility kernels
// ---------------------------------------------------------------------------

__global__ void zero_k(float* __restrict__ p, int n) {
    int i = blockIdx.x * blockDim.x + threadIdx.x;
    if (i < n) p[i] = 0.0f;
}

__global__ void bounds_k(const int* __restrict__ batch, int* __restrict__ starts) {
    int g = threadIdx.x;
    if (g <= GG) {
        int lo = 0, hi = NN;
        while (lo < hi) {
            int mid = (lo + hi) >> 1;
            if (batch[mid] < g) lo = mid + 1; else hi = mid;
        }
        starts[g] = lo;
    }
}

// fused: exact fp32 column stats of x (NN x 128) + bf16 cast, vectorized.
__global__ __launch_bounds__(256)
void colstats_cvt(const float* __restrict__ x, bf16* __restrict__ xb,
                  float* __restrict__ stats) {
    __shared__ float rs[4][128], rq[4][128];
    int t = threadIdx.x;
    int w = t >> 6, l = t & 63;
    int rg = t >> 5;      // 0..7 row-group
    int cq = t & 31;      // col-quad (4 cols)
    float s0 = 0, s1 = 0, s2 = 0, s3 = 0, q0 = 0, q1 = 0, q2 = 0, q3 = 0;
    for (int row = blockIdx.x * 8 + rg; row < NN; row += gridDim.x * 8) {
        float4 v = *(const float4*)&x[(size_t)row * INF + cq * 4];
        bf16x4 o; o[0] = (bf16)v.x; o[1] = (bf16)v.y; o[2] = (bf16)v.z; o[3] = (bf16)v.w;
        *(bf16x4*)&xb[(size_t)row * INF + cq * 4] = o;
        s0 += v.x; q0 += v.x * v.x;
        s1 += v.y; q1 += v.y * v.y;
        s2 += v.z; q2 += v.z * v.z;
        s3 += v.w; q3 += v.w * v.w;
    }
    s0 += __shfl_xor(s0, 32); s1 += __shfl_xor(s1, 32);
    s2 += __shfl_xor(s2, 32); s3 += __shfl_xor(s3, 32);
    q0 += __shfl_xor(q0, 32); q1 += __shfl_xor(q1, 32);
    q2 += __shfl_xor(q2, 32); q3 += __shfl_xor(q3, 32);
    if (l < 32) {
        rs[w][cq * 4 + 0] = s0; rs[w][cq * 4 + 1] = s1;
        rs[w][cq * 4 + 2] = s2; rs[w][cq * 4 + 3] = s3;
        rq[w][cq * 4 + 0] = q0; rq[w][cq * 4 + 1] = q1;
        rq[w][cq * 4 + 2] = q2; rq[w][cq * 4 + 3] = q3;
    }
    __syncthreads();
    if (t < 128) {
        atomicAdd(&stats[t],       rs[0][t] + rs[1][t] + rs[2][t] + rs[3][t]);
        atomicAdd(&stats[INF + t], rq[0][t] + rq[1][t] + rq[2][t] + rq[3][t]);
    }
}

// Wt[j][k] = bf16( s[k] * W[k][j] ) via LDS 64x64 tile transpose.
// s computed inline from stats/gamma (stats==null -> s=1).
__global__ __launch_bounds__(256)
void fold_wt(const float* __restrict__ stats, const float* __restrict__ gamma,
             const float* __restrict__ W, bf16* __restrict__ Wt, int K) {
    __shared__ float tile[64][68];
    __shared__ float sarr[64];
    int j0 = blockIdx.x * 64, k0 = blockIdx.y * 64;
    int t = threadIdx.x;
    if (t < 64) sarr[t] = stats ? bn_s(stats, gamma, K, k0 + t) : 1.0f;
    int kk = t >> 2, jq = t & 3;
#pragma unroll
    for (int i = 0; i < 4; i++) {
        float4 v = *(const float4*)&W[(size_t)(k0 + kk) * DD + j0 + jq * 16 + i * 4];
        *(float4*)&tile[kk][jq * 16 + i * 4] = v;
    }
    __syncthreads();
    int jj = t >> 2, kq = t & 3;
    bf16 ov[16];
#pragma unroll
    for (int i = 0; i < 16; i++)
        ov[i] = (bf16)(tile[kq * 16 + i][jj] * sarr[kq * 16 + i]);
    bf16* dst = &Wt[(size_t)(j0 + jj) * K + k0 + kq * 16];
    *(u32x4*)dst       = *(u32x4*)&ov[0];
    *(u32x4*)(dst + 8) = *(u32x4*)&ov[8];
}

// bp[j] = b[j] + sum_k t[k]*W[k][j]; t computed inline. grid 8, block 256.
__global__ __launch_bounds__(256)
void fold_b(const float* __restrict__ stats, const float* __restrict__ gamma,
            const float* __restrict__ beta, const float* __restrict__ W,
            const float* __restrict__ b, float* __restrict__ bp, int K) {
    __shared__ float red[4][64];
    __shared__ float tt[DD];
    int t = threadIdx.x;
    for (int k = t; k < K; k += 256) tt[k] = bn_t(stats, gamma, beta, K, k);
    __syncthreads();
    int jj = t & 63, kr = t >> 6;
    int j = blockIdx.x * 64 + jj;
    float acc = 0.f;
    for (int k = kr; k < K; k += 4)
        acc += tt[k] * W[(size_t)k * DD + j];
    red[kr][jj] = acc;
    __syncthreads();
    if (kr == 0) bp[j] = b[j] + red[0][jj] + red[1][jj] + red[2][jj] + red[3][jj];
}

// ---------------------------------------------------------------------------
// MFMA GEMM, global_load_lds staging + XOR slot swizzle + XCD-aware mapping.
// A: M x K bf16, Wt: 512 x K bf16 (pre-T). 1D grid GEMM_GRID:
//   xcd = id&7 (HW round-robin), j = id>>3, yb = xcd*CPX + (j>>2), x = j&3.
// Each XCD owns a contiguous row-block band and runs all 4 col-blocks of a
// row-block back-to-back -> A-tile L2-resident (fetch once/XCD), Wt (0.5MB)
// permanently L2-resident. Converts staging loads from ~900cy HBM to ~200cy L2.
// LDS tiles LINEAR [128][64] bf16; slot permutation (slot ^ (row&7)) applied
// to BOTH global source and ds_read -> conflict-free (verified r10: 0 confl).
// MODE 0: plain store. MODE 1: + fused column sum/sumsq.
// MODE 2: stats + segment-pool into R, NO H store.
// ---------------------------------------------------------------------------
template <int K, int MODE>
__global__ __launch_bounds__(256, 4)
void gemm_mfma(const bf16* __restrict__ A, const bf16* __restrict__ Wt,
               const float* __restrict__ bias, bf16* __restrict__ H, int M,
               float* __restrict__ stats, const int* __restrict__ batch,
               float* __restrict__ R) {
    const int id  = blockIdx.x;
    const int xcd = id & 7;
    const int jj  = id >> 3;
    const int yb  = xcd * CPX + (jj >> 2);
    if (yb >= NRB) return;                       // padded tail
    const int col0 = (jj & 3) * 128;
    const int row0 = yb * 128;

    __shared__ bf16 smem[18432];                 // As(16K)|Bs(16K); C-tile reuse
    bf16* As = smem;                             // [128][64] linear
    bf16* Bs = smem + 8192;
    const int t  = threadIdx.x;
    const int l  = t & 63;
    const int w  = t >> 6;
    const int wr = w >> 1, wc = w & 1;

    // staging geometry: thread covers rows c*32 + w*8 + (l>>3), slot l&7
    const int srow = w * 8 + (l >> 3);
    const int sslt = l & 7;

    f32x4 acc[4][4];
#pragma unroll
    for (int m = 0; m < 4; m++)
#pragma unroll
        for (int n = 0; n < 4; n++) acc[m][n] = (f32x4){0.f, 0.f, 0.f, 0.f};

#pragma unroll 1
    for (int k0 = 0; k0 < K; k0 += 64) {
#pragma unroll
        for (int c = 0; c < 4; c++) {
            int r  = c * 32 + srow;              // LDS row 0..127
            int sg = sslt ^ (r & 7);             // pre-swizzled source slot
            int ga = row0 + r; if (ga >= M) ga = M - 1;
            gld16(A  + (size_t)ga * K + k0 + sg * 8,
                  (bf16*)((char*)As + c * 4096 + w * 1024));
            gld16(Wt + (size_t)(col0 + r) * K + k0 + sg * 8,
                  (bf16*)((char*)Bs + c * 4096 + w * 1024));
        }
        __syncthreads();                         // drains vmcnt before barrier
#pragma unroll
        for (int ks = 0; ks < 2; ks++) {
            bf16x8 af[4], bfr[4];
#pragma unroll
            for (int m = 0; m < 4; m++) {
                int r = wr * 64 + m * 16 + (l & 15);
                af[m] = *(const bf16x8*)((const char*)As + r * 128 +
                        ((((ks << 2) + (l >> 4)) ^ (r & 7)) << 4));
            }
#pragma unroll
            for (int n = 0; n < 4; n++) {
                int r = wc * 64 + n * 16 + (l & 15);
                bfr[n] = *(const bf16x8*)((const char*)Bs + r * 128 +
                         ((((ks << 2) + (l >> 4)) ^ (r & 7)) << 4));
            }
#pragma unroll
            for (int m = 0; m < 4; m++)
#pragma unroll
                for (int n = 0; n < 4; n++)
                    acc[m][n] = __builtin_amdgcn_mfma_f32_16x16x32_bf16(af[m], bfr[n], acc[m][n], 0, 0, 0);
        }
        __syncthreads();
    }

    float csumA[4], csqA[4];

    if (MODE <= 1) {
        // bias+relu -> C-tile in LDS (stride 136 bf16 = 272B), stats in regs
        bf16* ct = smem;
#pragma unroll
        for (int n = 0; n < 4; n++) {
            int lc = wc * 64 + n * 16 + (l & 15);
            float bv = bias[col0 + lc];
            float cs = 0.f, cq = 0.f;
#pragma unroll
            for (int m = 0; m < 4; m++) {
#pragma unroll
                for (int q = 0; q < 4; q++) {
                    int lr = wr * 64 + m * 16 + (l >> 4) * 4 + q;
                    float v = acc[m][n][q] + bv;
                    v = v > 0.f ? v : 0.f;
                    ct[lr * 136 + lc] = (bf16)v;
                    if (MODE == 1 && row0 + lr < M) { cs += v; cq += v * v; }
                }
            }
            csumA[n] = cs; csqA[n] = cq;
        }
        __syncthreads();
        // coalesced store: 8 iters x 256 threads x 16B = 32KB tile
        {
            const char* cts = (const char*)ct;
            char* Hc = (char*)H;
#pragma unroll
            for (int i = 0; i < 8; i++) {
                int fo = i * 4096 + t * 16;
                int r  = fo >> 8;          // tile row (256B of payload per row)
                int cb = fo & 255;
                if (row0 + r < M)
                    *(u32x4*)(Hc + ((size_t)(row0 + r) * (DD * 2) + (size_t)col0 * 2 + cb)) =
                        *(const u32x4*)(cts + r * 272 + cb);
            }
        }
    } else {
        // MODE 2: stats + segment-pool straight from registers; no H store.
        int gid[4][4];
#pragma unroll
        for (int m = 0; m < 4; m++)
#pragma unroll
            for (int q = 0; q < 4; q++) {
                int grow = row0 + wr * 64 + m * 16 + (l >> 4) * 4 + q;
                gid[m][q] = (grow < M) ? batch[grow] : -1;
            }
#pragma unroll
        for (int n = 0; n < 4; n++) {
            int col = col0 + wc * 64 + n * 16 + (l & 15);
            float bv = bias[col];
            float cs = 0.f, cq = 0.f;
            float ps = 0.f; int gc = -1;
#pragma unroll
            for (int m = 0; m < 4; m++) {
#pragma unroll
                for (int q = 0; q < 4; q++) {
                    int g = gid[m][q];
                    if (g >= 0) {
                        float v = acc[m][n][q] + bv;
                        v = v > 0.f ? v : 0.f;
                        cs += v; cq += v * v;
                        if (g != gc) {
                            if (gc >= 0) atomicAdd(&R[(size_t)gc * DD + col], ps);
                            ps = 0.f; gc = g;
                        }
                        ps += v;
                    }
                }
            }
            if (gc >= 0) atomicAdd(&R[(size_t)gc * DD + col], ps);
            csumA[n] = cs; csqA[n] = cq;
        }
    }

    if (MODE >= 1) {
#pragma unroll
        for (int n = 0; n < 4; n++) {
            float cs = csumA[n], cq = csqA[n];
            cs += __shfl_xor(cs, 16); cs += __shfl_xor(cs, 32);
            cq += __shfl_xor(cq, 16); cq += __shfl_xor(cq, 32);
            if ((l >> 4) == 0) {
                int col = col0 + wc * 64 + n * 16 + l;
                atomicAdd(&stats[col], cs);
                atomicAdd(&stats[DD + col], cq);
            }
        }
    }
}

// P[g][j] = R[g][j]*s4[j] + cnt_g*t4[j]; s4/t4 computed inline from stats4.
__global__ __launch_bounds__(512)
void pool_fin(const float* __restrict__ R, const int* __restrict__ starts,
              const float* __restrict__ stats, const float* __restrict__ gamma,
              const float* __restrict__ beta, float* __restrict__ P) {
    int g = blockIdx.x, j = threadIdx.x;
    float sv = bn_s(stats, gamma, DD, j);
    float tv = bn_t(stats, gamma, beta, DD, j);
    float cnt = (float)(starts[g + 1] - starts[g]);
    P[g * DD + j] = R[(size_t)g * DD + j] * sv + cnt * tv;
}

// ---------------------------------------------------------------------------
// head: per-graph  prelu(P@fc1+b) -> sigmoid(@fc2+b) -> @fc3+b  (fp32)
// ---------------------------------------------------------------------------
__global__ __launch_bounds__(256)
void head_k(const float* __restrict__ P,
            const float* __restrict__ fc1_w, const float* __restrict__ fc1_b,
            const float* __restrict__ fc2_w, const float* __restrict__ fc2_b,
            const float* __restrict__ fc3_w, const float* __restrict__ fc3_b,
            const float* __restrict__ a3, float* __restrict__ out) {
    __shared__ float p[DD], y1[DD], y2[DD / 2];
    int g = blockIdx.x, t = threadIdx.x;
    p[t]       = P[g * DD + t];
    p[t + 256] = P[g * DD + t + 256];
    __syncthreads();
    float alpha = a3[0];

    float acc0 = fc1_b[t], acc1 = fc1_b[t + 256];
    for (int k = 0; k < DD; k++) {
        float pv = p[k];
        acc0 = fmaf(pv, fc1_w[(size_t)k * DD + t], acc0);
        acc1 = fmaf(pv, fc1_w[(size_t)k * DD + t + 256], acc1);
    }
    y1[t]       = acc0 >= 0.f ? acc0 : alpha * acc0;
    y1[t + 256] = acc1 >= 0.f ? acc1 : alpha * acc1;
    __syncthreads();

    float acc = fc2_b[t];
    for (int k = 0; k < DD; k++) acc = fmaf(y1[k], fc2_w[(size_t)k * (DD / 2) + t], acc);
    y2[t] = 1.0f / (1.0f + expf(-acc));
    __syncthreads();

    if (t < CC) {
        float a = fc3_b[t];
        for (int k = 0; k < DD / 2; k++) a = fmaf(y2[k], fc3_w[(size_t)k * CC + t], a);
        out[g * CC + t] = a;
    }
}

// ---------------------------------------------------------------------------
// launch
// ---------------------------------------------------------------------------
extern "C" void kernel_launch(void* const* d_in, const int* in_sizes, int n_in,
                              void* d_out, int out_size, void* d_ws, size_t ws_size,
                              hipStream_t stream) {
    const float* x     = (const float*)d_in[0];
    /* d_in[1] edge_index: unused (ChebConv K=1 == linear) */
    const int*   batch = (const int*)d_in[2];
    const float* bn1_g = (const float*)d_in[3];
    const float* bn1_b = (const float*)d_in[4];
    const float* w0    = (const float*)d_in[5];
    const float* b0    = (const float*)d_in[6];
    const float* w1    = (const float*)d_in[7];
    const float* bb1   = (const float*)d_in[8];
    const float* w2    = (const float*)d_in[9];
    const float* bb2   = (const float*)d_in[10];
    const float* w3    = (const float*)d_in[11];
    const float* bb3   = (const float*)d_in[12];
    const float* bn3_g = (const float*)d_in[13];
    const float* bn3_b = (const float*)d_in[14];
    const float* a3    = (const float*)d_in[15];
    const float* fc1_w = (const float*)d_in[16];
    const float* fc1_b = (const float*)d_in[17];
    const float* fc2_w = (const float*)d_in[18];
    const float* fc2_b = (const float*)d_in[19];
    const float* fc3_w = (const float*)d_in[20];
    const float* fc3_b = (const float*)d_in[21];
    float* out = (float*)d_out;

    // ---- workspace layout ----
    char* base = (char*)d_ws;
    const size_t HBYTES = (size_t)NN * DD * 2;       // 102,400,000
    bf16* Ha = (bf16*)base;
    bf16* Hb = (bf16*)(base + HBYTES);
    bf16* Xb = Hb;                                   // alias: dead after layer0
    bf16* Wt = (bf16*)(base + 2 * HBYTES);           // 512*512*2 = 524,288
    float* f = (float*)(base + 2 * HBYTES + 524288);
    size_t off = 0;
    float* stats  = f + off; off += 3328;            // x(256) + 3 layers (1024 each)
    float* R      = f + off; off += (size_t)GG * DD; // 32,768 (zeroed with stats)
    float* statsX = stats;
    float* stats2 = stats + 256;
    float* stats3 = stats + 1280;
    float* stats4 = stats + 2304;
    float* b0p = f + off; off += 512;
    float* bp  = f + off; off += 512;
    float* P   = f + off; off += (size_t)GG * DD;    // 32,768
    int*   starts = (int*)(f + off); off += 128;

    (void)in_sizes; (void)n_in; (void)out_size; (void)ws_size;

    const int kZeroCount = 3328 + GG * DD;           // stats + R contiguous

    zero_k<<<(kZeroCount + 255) / 256, 256, 0, stream>>>(stats, kZeroCount);
    bounds_k<<<1, 128, 0, stream>>>(batch, starts);

    // BN1 (exact fp32 stats on x) fused with bf16 cast; fold into layer0
    colstats_cvt<<<256, 256, 0, stream>>>(x, Xb, statsX);
    fold_wt<<<dim3(8, INF / 64), 256, 0, stream>>>(statsX, bn1_g, w0, Wt, INF);
    fold_b<<<8, 256, 0, stream>>>(statsX, bn1_g, bn1_b, w0, b0, b0p, INF);
    // layer0: Ha = relu(Xb @ W0' + b0')
    gemm_mfma<INF, 0><<<GEMM_GRID, 256, 0, stream>>>(Xb, Wt, b0p, Ha, NN, nullptr, nullptr, nullptr);

    // layer1: Hb = relu(Ha @ w1 + bb1) + fused stats2
    fold_wt<<<dim3(8, DD / 64), 256, 0, stream>>>(nullptr, nullptr, w1, Wt, DD);
    gemm_mfma<DD, 1><<<GEMM_GRID, 256, 0, stream>>>(Ha, Wt, bb1, Hb, NN, stats2, nullptr, nullptr);

    // layer2: fold BN(stats2) into w2; Ha = relu(Hb @ W2' + b2') + stats3
    fold_wt<<<dim3(8, DD / 64), 256, 0, stream>>>(stats2, bn3_g, w2, Wt, DD);
    fold_b<<<8, 256, 0, stream>>>(stats2, bn3_g, bn3_b, w2, bb2, bp, DD);
    gemm_mfma<DD, 1><<<GEMM_GRID, 256, 0, stream>>>(Hb, Wt, bp, Ha, NN, stats3, nullptr, nullptr);

    // layer3: fold BN(stats3) into w3; stats4 + segment-pool fused, no H store
    fold_wt<<<dim3(8, DD / 64), 256, 0, stream>>>(stats3, bn3_g, w3, Wt, DD);
    fold_b<<<8, 256, 0, stream>>>(stats3, bn3_g, bn3_b, w3, bb3, bp, DD);
    gemm_mfma<DD, 2><<<GEMM_GRID, 256, 0, stream>>>(Ha, Wt, bp, nullptr, NN, stats4, batch, R);

    // final BN folded into pooled sums (s4/t4 inline)
    pool_fin<<<GG, 512, 0, stream>>>(R, starts, stats4, bn3_g, bn3_b, P);
    head_k<<<GG, 256, 0, stream>>>(P, fc1_w, fc1_b, fc2_w, fc2_b, fc3_w, fc3_b, a3, out);
}